// Round 6
// baseline (689.754 us; speedup 1.0000x reference)
//
#include <hip/hip_runtime.h>
#include <math.h>

// ---------------------------------------------------------------------------
// GATv2 encoder (2x GATv2Conv share_weights + GELU, head Linear+LayerNorm).
// NOTE: harness delivers integer inputs as int32 — edge_index is const int*
// (reading it as int64 was the cause of the round-2..5 page-fault aborts).
// Workspace-adaptive: h stored f32 if ws_size permits else bf16; layer
// activations x stored bf16 inside d_out (N*D*2 == NT*D*4 bytes here).
// CSR-by-dst built once; fused logits+softmax+aggregate, wave per dst node.
// ---------------------------------------------------------------------------

#define D 128
#define H 8
#define C 16

static __device__ __forceinline__ float bf2f(unsigned int u16) {
    union { unsigned int i; float f; } x; x.i = u16 << 16; return x.f;
}
static __device__ __forceinline__ unsigned short f2bf(float f) {
    union { float f; unsigned int i; } x; x.f = f;
    unsigned int r = x.i + 0x7fffu + ((x.i >> 16) & 1u);   // RNE
    return (unsigned short)(r >> 16);
}
static __device__ __forceinline__ float gelu_f(float v) {
    return 0.5f * v * (1.0f + erff(v * 0.70710678118654752f));
}

// ----------------------------- GEMM ---------------------------------------
// Out[nrows x 128] = act(X[nrows x 128]) @ W[128 x 128] (+ bias)
// IN_BF / OUT_BF select bf16 vs f32 storage for X / Out. GELU on X load.
template<int IN_BF, int OUT_BF, int GELU>
__global__ __launch_bounds__(256) void gemm128(
    const void* __restrict__ Xv, const float* __restrict__ Wg,
    const float* __restrict__ bias, void* __restrict__ Outv, int nrows)
{
    __shared__ float xs[64][65];
    __shared__ float ws[64][128];

    const int t  = threadIdx.x;
    const int tx = t & 15;
    const int ty = t >> 4;
    const int m0 = blockIdx.x * 64;

    float acc[4][8];
#pragma unroll
    for (int i = 0; i < 4; ++i)
#pragma unroll
        for (int j = 0; j < 8; ++j) acc[i][j] = 0.f;

    for (int kc = 0; kc < 2; ++kc) {
#pragma unroll
        for (int it = 0; it < 4; ++it) {
            int idx = it * 256 + t;          // 4-elem units, 0..1023
            int r   = idx >> 4;              // 0..63
            int c4  = idx & 15;              // 0..15
            float v0 = 0.f, v1 = 0.f, v2 = 0.f, v3 = 0.f;
            if (m0 + r < nrows) {
                if (IN_BF) {
                    ushort4 u = reinterpret_cast<const ushort4*>(Xv)
                                    [(size_t)(m0 + r) * 32 + kc * 16 + c4];
                    v0 = bf2f(u.x); v1 = bf2f(u.y); v2 = bf2f(u.z); v3 = bf2f(u.w);
                } else {
                    float4 u = reinterpret_cast<const float4*>(Xv)
                                   [(size_t)(m0 + r) * 32 + kc * 16 + c4];
                    v0 = u.x; v1 = u.y; v2 = u.z; v3 = u.w;
                }
            }
            if (GELU) { v0 = gelu_f(v0); v1 = gelu_f(v1); v2 = gelu_f(v2); v3 = gelu_f(v3); }
            xs[r][c4 * 4 + 0] = v0;
            xs[r][c4 * 4 + 1] = v1;
            xs[r][c4 * 4 + 2] = v2;
            xs[r][c4 * 4 + 3] = v3;
        }
#pragma unroll
        for (int it = 0; it < 8; ++it) {
            int idx = it * 256 + t;          // float4 units, 0..2047
            int r   = idx >> 5;              // 0..63
            int c4  = idx & 31;              // 0..31
            float4 v = reinterpret_cast<const float4*>(Wg)[(size_t)(kc * 64 + r) * 32 + c4];
            reinterpret_cast<float4*>(&ws[r][0])[c4] = v;
        }
        __syncthreads();

#pragma unroll
        for (int kk = 0; kk < 64; ++kk) {
            float a[4];
#pragma unroll
            for (int i = 0; i < 4; ++i) a[i] = xs[ty * 4 + i][kk];
            float4 b0 = reinterpret_cast<float4*>(&ws[kk][0])[tx * 2 + 0];
            float4 b1 = reinterpret_cast<float4*>(&ws[kk][0])[tx * 2 + 1];
            float b[8] = {b0.x, b0.y, b0.z, b0.w, b1.x, b1.y, b1.z, b1.w};
#pragma unroll
            for (int i = 0; i < 4; ++i)
#pragma unroll
                for (int j = 0; j < 8; ++j) acc[i][j] += a[i] * b[j];
        }
        __syncthreads();
    }

#pragma unroll
    for (int i = 0; i < 4; ++i) {
        int r = m0 + ty * 4 + i;
        if (r < nrows) {
            float o[8];
#pragma unroll
            for (int j = 0; j < 8; ++j)
                o[j] = acc[i][j] + (bias ? bias[tx * 8 + j] : 0.f);
            if (OUT_BF) {
                uint4 pk;
                pk.x = (unsigned int)f2bf(o[0]) | ((unsigned int)f2bf(o[1]) << 16);
                pk.y = (unsigned int)f2bf(o[2]) | ((unsigned int)f2bf(o[3]) << 16);
                pk.z = (unsigned int)f2bf(o[4]) | ((unsigned int)f2bf(o[5]) << 16);
                pk.w = (unsigned int)f2bf(o[6]) | ((unsigned int)f2bf(o[7]) << 16);
                reinterpret_cast<uint4*>(Outv)[(size_t)r * 16 + tx] = pk;
            } else {
                float4 o0 = make_float4(o[0], o[1], o[2], o[3]);
                float4 o1 = make_float4(o[4], o[5], o[6], o[7]);
                reinterpret_cast<float4*>(Outv)[(size_t)r * 32 + tx * 2 + 0] = o0;
                reinterpret_cast<float4*>(Outv)[(size_t)r * 32 + tx * 2 + 1] = o1;
            }
        }
    }
}

// ------------------------- CSR build kernels -------------------------------
__global__ void zero_ints(int* __restrict__ p, int n)
{
    int stride = gridDim.x * blockDim.x;
    for (int i = blockIdx.x * blockDim.x + threadIdx.x; i < n; i += stride) p[i] = 0;
}

__global__ void count_edges(const int* __restrict__ dst, int* __restrict__ cnt, int E)
{
    int t = blockIdx.x * blockDim.x + threadIdx.x;
    if (t < E) atomicAdd(&cnt[dst[t]], 1);
}

__global__ __launch_bounds__(1024) void scan_kernel(
    const int* __restrict__ cnt, int* __restrict__ rowptr, int n)
{
    __shared__ int buf[1024];
    __shared__ int carry;
    int t = threadIdx.x;
    if (t == 0) { carry = 0; rowptr[0] = 0; }
    __syncthreads();
    for (int base = 0; base < n; base += 1024) {
        int v = (base + t < n) ? cnt[base + t] : 0;
        buf[t] = v;
        __syncthreads();
        for (int off = 1; off < 1024; off <<= 1) {
            int x = 0;
            if (t >= off) x = buf[t - off];
            __syncthreads();
            buf[t] += x;
            __syncthreads();
        }
        int inc = buf[t];
        if (base + t < n) rowptr[base + t + 1] = carry + inc;
        __syncthreads();
        if (t == 1023) carry += buf[1023];
        __syncthreads();
    }
}

// stores SOURCE node index grouped by destination
__global__ void scatter_edges(const int* __restrict__ dst,
                              const int* __restrict__ src,
                              const int* __restrict__ rowptr,
                              int* __restrict__ cursor,
                              int* __restrict__ slist, int E)
{
    int t = blockIdx.x * blockDim.x + threadIdx.x;
    if (t < E) {
        int d = dst[t];
        int p = rowptr[d] + atomicAdd(&cursor[d], 1);
        slist[p] = src[t];
    }
}

// --------------- fused logits + softmax + aggregate ------------------------
// wave per dst node; lane holds channels (2*lane, 2*lane+1); head = lane>>3.
// HBF: h stored bf16 (packed pairs) vs f32. Output x always packed bf16.
template<int HBF>
__global__ __launch_bounds__(256) void aggregate(
    const void* __restrict__ Hm,
    const int* __restrict__ rowptr, const int* __restrict__ slist,
    const float* __restrict__ att, const float* __restrict__ bias,
    unsigned int* __restrict__ Outv, int n)
{
    int wid  = threadIdx.x >> 6;
    int lane = threadIdx.x & 63;
    int d = blockIdx.x * 4 + wid;
    if (d >= n) return;

    int beg = rowptr[d];
    int end = rowptr[d + 1];

    float hdx, hdy;
    if (HBF) {
        unsigned int u = reinterpret_cast<const unsigned int*>(Hm)[(size_t)d * 64 + lane];
        hdx = bf2f(u & 0xffffu); hdy = bf2f(u >> 16);
    } else {
        float2 h2 = reinterpret_cast<const float2*>(Hm)[(size_t)d * 64 + lane];
        hdx = h2.x; hdy = h2.y;
    }
    float2 aw = reinterpret_cast<const float2*>(att)[lane];

    float m = -3.4e38f;
    for (int i = beg; i < end; ++i) {
        int s = slist[i];
        float hx, hy;
        if (HBF) {
            unsigned int u = reinterpret_cast<const unsigned int*>(Hm)[(size_t)s * 64 + lane];
            hx = bf2f(u & 0xffffu); hy = bf2f(u >> 16);
        } else {
            float2 h2 = reinterpret_cast<const float2*>(Hm)[(size_t)s * 64 + lane];
            hx = h2.x; hy = h2.y;
        }
        float v0 = hx + hdx; v0 = v0 > 0.f ? v0 : 0.2f * v0;
        float v1 = hy + hdy; v1 = v1 > 0.f ? v1 : 0.2f * v1;
        float p = v0 * aw.x + v1 * aw.y;
        p += __shfl_xor(p, 1); p += __shfl_xor(p, 2); p += __shfl_xor(p, 4);
        m = fmaxf(m, p);
    }

    float ssum = 0.f;
    float accx = 0.f, accy = 0.f;
    for (int i = beg; i < end; ++i) {
        int s = slist[i];
        float hx, hy;
        if (HBF) {
            unsigned int u = reinterpret_cast<const unsigned int*>(Hm)[(size_t)s * 64 + lane];
            hx = bf2f(u & 0xffffu); hy = bf2f(u >> 16);
        } else {
            float2 h2 = reinterpret_cast<const float2*>(Hm)[(size_t)s * 64 + lane];
            hx = h2.x; hy = h2.y;
        }
        float v0 = hx + hdx; v0 = v0 > 0.f ? v0 : 0.2f * v0;
        float v1 = hy + hdy; v1 = v1 > 0.f ? v1 : 0.2f * v1;
        float p = v0 * aw.x + v1 * aw.y;
        p += __shfl_xor(p, 1); p += __shfl_xor(p, 2); p += __shfl_xor(p, 4);
        float ex = expf(p - m);
        ssum += ex;
        accx += ex * hx;
        accy += ex * hy;
    }
    float inv = 1.f / (ssum + 1e-16f);
    float2 bv = reinterpret_cast<const float2*>(bias)[lane];
    float ox = accx * inv + bv.x;
    float oy = accy * inv + bv.y;
    Outv[(size_t)d * 64 + lane] =
        (unsigned int)f2bf(ox) | ((unsigned int)f2bf(oy) << 16);
}

// ------------------------------ LayerNorm ----------------------------------
// reads f32 Y (ws), writes f32 Out (d_out)
__global__ __launch_bounds__(256) void ln_kernel(
    const float* __restrict__ Y, const float* __restrict__ g,
    const float* __restrict__ b, float* __restrict__ Out, int n)
{
    int wid  = threadIdx.x >> 6;
    int lane = threadIdx.x & 63;
    int r = blockIdx.x * 4 + wid;
    if (r >= n) return;

    float2 v = reinterpret_cast<const float2*>(Y)[(size_t)r * 64 + lane];
    float sum = v.x + v.y;
#pragma unroll
    for (int off = 32; off >= 1; off >>= 1) sum += __shfl_xor(sum, off);
    float mu = sum * (1.f / 128.f);
    float dx = v.x - mu, dy = v.y - mu;
    float sq = dx * dx + dy * dy;
#pragma unroll
    for (int off = 32; off >= 1; off >>= 1) sq += __shfl_xor(sq, off);
    float inv = rsqrtf(sq * (1.f / 128.f) + 1e-12f);
    float2 gv = reinterpret_cast<const float2*>(g)[lane];
    float2 bv = reinterpret_cast<const float2*>(b)[lane];
    float2 o;
    o.x = dx * inv * gv.x + bv.x;
    o.y = dy * inv * gv.y + bv.y;
    reinterpret_cast<float2*>(Out)[(size_t)r * 64 + lane] = o;
}

// ---------------------------------------------------------------------------
extern "C" void kernel_launch(void* const* d_in, const int* in_sizes, int n_in,
                              void* d_out, int out_size, void* d_ws, size_t ws_size,
                              hipStream_t stream)
{
    const float* x    = (const float*)d_in[0];
    const int*   edge = (const int*)d_in[1];     // int32! (harness converts int64)
    const float* W    = (const float*)d_in[2];
    const float* att  = (const float*)d_in[3];
    const float* bias = (const float*)d_in[4];
    const float* outW = (const float*)d_in[5];
    const float* outb = (const float*)d_in[6];
    const float* lng  = (const float*)d_in[7];
    const float* lnb  = (const float*)d_in[8];

    const int N  = in_sizes[0] / D;
    const int E  = in_sizes[1] / 2;
    const int NT = out_size / D;

    const int* srcp = edge;
    const int* dstp = edge + E;

    auto align256 = [](size_t v) { return (v + 255) & ~(size_t)255; };
    auto cdiv = [](int a, int b) { return (a + b - 1) / b; };

    // fixed small buffers
    size_t fixed = align256((size_t)(N + 1) * 4) + align256((size_t)N * 4)
                 + align256((size_t)E * 4);
    size_t ybytes = (size_t)NT * D * 4;
    size_t h_f32  = align256((size_t)N * D * 4 > ybytes ? (size_t)N * D * 4 : ybytes);
    size_t h_bf   = align256((size_t)N * D * 2 > ybytes ? (size_t)N * D * 2 : ybytes);
    const bool hf32 = (ws_size >= h_f32 + fixed);
    size_t hbytes = hf32 ? h_f32 : h_bf;

    char* wp = (char*)d_ws;
    size_t off = 0;
    void*  hbuf   = (void*)(wp + off); off += hbytes;
    int*   rowptr = (int*)(wp + off);  off = off + align256((size_t)(N + 1) * 4);
    int*   cnt    = (int*)(wp + off);  off = off + align256((size_t)N * 4);
    int*   slist  = (int*)(wp + off);
    // x activations live in d_out as packed bf16 (N*D*2 <= NT*D*4 required;
    // holds here since N == 2*NT). Final f32 output overwrites at the end.
    unsigned int* xb = (unsigned int*)d_out;
    float* ybuf = (float*)hbuf;        // head GEMM output reuses dead h buffer
    (void)n_in;

    // ---- CSR build ----
    zero_ints<<<cdiv(N, 256), 256, 0, stream>>>(cnt, N);
    count_edges<<<cdiv(E, 256), 256, 0, stream>>>(dstp, cnt, E);
    scan_kernel<<<1, 1024, 0, stream>>>(cnt, rowptr, N);
    zero_ints<<<cdiv(N, 256), 256, 0, stream>>>(cnt, N);
    scatter_edges<<<cdiv(E, 256), 256, 0, stream>>>(dstp, srcp, rowptr, cnt, slist, E);

    if (hf32) {
        gemm128<0,0,0><<<cdiv(N, 64), 256, 0, stream>>>(x, W, nullptr, hbuf, N);
        aggregate<0><<<cdiv(N, 4), 256, 0, stream>>>(hbuf, rowptr, slist, att, bias, xb, N);
        gemm128<1,0,1><<<cdiv(N, 64), 256, 0, stream>>>(xb, W + D * D, nullptr, hbuf, N);
        aggregate<0><<<cdiv(N, 4), 256, 0, stream>>>(hbuf, rowptr, slist, att + H * C, bias + D, xb, N);
        gemm128<1,0,0><<<cdiv(NT, 64), 256, 0, stream>>>(xb, outW, outb, ybuf, NT);
    } else {
        gemm128<0,1,0><<<cdiv(N, 64), 256, 0, stream>>>(x, W, nullptr, hbuf, N);
        aggregate<1><<<cdiv(N, 4), 256, 0, stream>>>(hbuf, rowptr, slist, att, bias, xb, N);
        gemm128<1,1,1><<<cdiv(N, 64), 256, 0, stream>>>(xb, W + D * D, nullptr, hbuf, N);
        aggregate<1><<<cdiv(N, 4), 256, 0, stream>>>(hbuf, rowptr, slist, att + H * C, bias + D, xb, N);
        gemm128<1,0,0><<<cdiv(NT, 64), 256, 0, stream>>>(xb, outW, outb, ybuf, NT);
    }
    ln_kernel<<<cdiv(NT, 4), 256, 0, stream>>>(ybuf, lng, lnb, (float*)d_out, NT);
}

// Round 7
// 359.490 us; speedup vs baseline: 1.9187x; 1.9187x over previous
//
#include <hip/hip_runtime.h>
#include <math.h>

// ---------------------------------------------------------------------------
// GATv2 encoder (2x GATv2Conv share_weights + GELU, head Linear+LayerNorm).
// edge_index arrives as int32. h always bf16 (halves gather traffic; aggregate
// is gather-bound per r6 profile). Single-pass ONLINE-softmax aggregate
// (r6: two-pass aggregate was 2x206us = 60% of total). Multi-block scan
// (r6: single-block Hillis-Steele was a serial hidden cost).
// x activations stored bf16 inside d_out (N*D*2 == NT*D*4 here).
// ---------------------------------------------------------------------------

#define D 128
#define H 8
#define C 16

static __device__ __forceinline__ float bf2f(unsigned int u16) {
    union { unsigned int i; float f; } x; x.i = u16 << 16; return x.f;
}
static __device__ __forceinline__ unsigned short f2bf(float f) {
    union { float f; unsigned int i; } x; x.f = f;
    unsigned int r = x.i + 0x7fffu + ((x.i >> 16) & 1u);   // RNE
    return (unsigned short)(r >> 16);
}
static __device__ __forceinline__ float gelu_f(float v) {
    return 0.5f * v * (1.0f + erff(v * 0.70710678118654752f));
}

// ----------------------------- GEMM ---------------------------------------
// Out[nrows x 128] = act(X[nrows x 128]) @ W[128 x 128] (+ bias)
template<int IN_BF, int OUT_BF, int GELU>
__global__ __launch_bounds__(256) void gemm128(
    const void* __restrict__ Xv, const float* __restrict__ Wg,
    const float* __restrict__ bias, void* __restrict__ Outv, int nrows)
{
    __shared__ float xs[64][65];
    __shared__ float ws[64][128];

    const int t  = threadIdx.x;
    const int tx = t & 15;
    const int ty = t >> 4;
    const int m0 = blockIdx.x * 64;

    float acc[4][8];
#pragma unroll
    for (int i = 0; i < 4; ++i)
#pragma unroll
        for (int j = 0; j < 8; ++j) acc[i][j] = 0.f;

    for (int kc = 0; kc < 2; ++kc) {
#pragma unroll
        for (int it = 0; it < 4; ++it) {
            int idx = it * 256 + t;
            int r   = idx >> 4;
            int c4  = idx & 15;
            float v0 = 0.f, v1 = 0.f, v2 = 0.f, v3 = 0.f;
            if (m0 + r < nrows) {
                if (IN_BF) {
                    ushort4 u = reinterpret_cast<const ushort4*>(Xv)
                                    [(size_t)(m0 + r) * 32 + kc * 16 + c4];
                    v0 = bf2f(u.x); v1 = bf2f(u.y); v2 = bf2f(u.z); v3 = bf2f(u.w);
                } else {
                    float4 u = reinterpret_cast<const float4*>(Xv)
                                   [(size_t)(m0 + r) * 32 + kc * 16 + c4];
                    v0 = u.x; v1 = u.y; v2 = u.z; v3 = u.w;
                }
            }
            if (GELU) { v0 = gelu_f(v0); v1 = gelu_f(v1); v2 = gelu_f(v2); v3 = gelu_f(v3); }
            xs[r][c4 * 4 + 0] = v0;
            xs[r][c4 * 4 + 1] = v1;
            xs[r][c4 * 4 + 2] = v2;
            xs[r][c4 * 4 + 3] = v3;
        }
#pragma unroll
        for (int it = 0; it < 8; ++it) {
            int idx = it * 256 + t;
            int r   = idx >> 5;
            int c4  = idx & 31;
            float4 v = reinterpret_cast<const float4*>(Wg)[(size_t)(kc * 64 + r) * 32 + c4];
            reinterpret_cast<float4*>(&ws[r][0])[c4] = v;
        }
        __syncthreads();

#pragma unroll
        for (int kk = 0; kk < 64; ++kk) {
            float a[4];
#pragma unroll
            for (int i = 0; i < 4; ++i) a[i] = xs[ty * 4 + i][kk];
            float4 b0 = reinterpret_cast<float4*>(&ws[kk][0])[tx * 2 + 0];
            float4 b1 = reinterpret_cast<float4*>(&ws[kk][0])[tx * 2 + 1];
            float b[8] = {b0.x, b0.y, b0.z, b0.w, b1.x, b1.y, b1.z, b1.w};
#pragma unroll
            for (int i = 0; i < 4; ++i)
#pragma unroll
                for (int j = 0; j < 8; ++j) acc[i][j] += a[i] * b[j];
        }
        __syncthreads();
    }

#pragma unroll
    for (int i = 0; i < 4; ++i) {
        int r = m0 + ty * 4 + i;
        if (r < nrows) {
            float o[8];
#pragma unroll
            for (int j = 0; j < 8; ++j)
                o[j] = acc[i][j] + (bias ? bias[tx * 8 + j] : 0.f);
            if (OUT_BF) {
                uint4 pk;
                pk.x = (unsigned int)f2bf(o[0]) | ((unsigned int)f2bf(o[1]) << 16);
                pk.y = (unsigned int)f2bf(o[2]) | ((unsigned int)f2bf(o[3]) << 16);
                pk.z = (unsigned int)f2bf(o[4]) | ((unsigned int)f2bf(o[5]) << 16);
                pk.w = (unsigned int)f2bf(o[6]) | ((unsigned int)f2bf(o[7]) << 16);
                reinterpret_cast<uint4*>(Outv)[(size_t)r * 16 + tx] = pk;
            } else {
                float4 o0 = make_float4(o[0], o[1], o[2], o[3]);
                float4 o1 = make_float4(o[4], o[5], o[6], o[7]);
                reinterpret_cast<float4*>(Outv)[(size_t)r * 32 + tx * 2 + 0] = o0;
                reinterpret_cast<float4*>(Outv)[(size_t)r * 32 + tx * 2 + 1] = o1;
            }
        }
    }
}

// ------------------------- CSR build kernels -------------------------------
__global__ void zero_ints(int* __restrict__ p, int n)
{
    int stride = gridDim.x * blockDim.x;
    for (int i = blockIdx.x * blockDim.x + threadIdx.x; i < n; i += stride) p[i] = 0;
}

__global__ void count_edges(const int* __restrict__ dst, int* __restrict__ cnt, int E)
{
    int t = blockIdx.x * blockDim.x + threadIdx.x;
    if (t < E) atomicAdd(&cnt[dst[t]], 1);
}

// ---- multi-block exclusive scan of cnt[0..n) into rowptr[1..n] ------------
// Phase A: 256 threads x 4 elems per block; block-inclusive scan + block sum.
__global__ __launch_bounds__(256) void scan_blocks(
    const int* __restrict__ cnt, int* __restrict__ rowptr,
    int* __restrict__ bsum, int n)
{
    __shared__ int sh[256];
    const int b = blockIdx.x, t = threadIdx.x;
    const int base = b * 1024 + t * 4;
    int v0 = 0, v1 = 0, v2 = 0, v3 = 0;
    if (base + 3 < n) {
        int4 q = *reinterpret_cast<const int4*>(cnt + base);
        v0 = q.x; v1 = q.y; v2 = q.z; v3 = q.w;
    } else {
        if (base     < n) v0 = cnt[base];
        if (base + 1 < n) v1 = cnt[base + 1];
        if (base + 2 < n) v2 = cnt[base + 2];
        if (base + 3 < n) v3 = cnt[base + 3];
    }
    int s = v0 + v1 + v2 + v3;
    sh[t] = s;
    __syncthreads();
#pragma unroll
    for (int off = 1; off < 256; off <<= 1) {
        int x = (t >= off) ? sh[t - off] : 0;
        __syncthreads();
        sh[t] += x;
        __syncthreads();
    }
    int excl = sh[t] - s;
    int p0 = excl + v0, p1 = p0 + v1, p2 = p1 + v2, p3 = p2 + v3;
    if (base     < n) rowptr[base + 1] = p0;
    if (base + 1 < n) rowptr[base + 2] = p1;
    if (base + 2 < n) rowptr[base + 3] = p2;
    if (base + 3 < n) rowptr[base + 4] = p3;
    if (t == 255) bsum[b] = sh[255];
}

// Phase B: single 64-thread block scans block sums (inclusive, with carry).
__global__ void scan_bsums(int* __restrict__ bsum, int nb)
{
    __shared__ int carry;
    int t = threadIdx.x & 63;
    if (threadIdx.x == 0) carry = 0;
    __syncthreads();
    for (int base = 0; base < nb; base += 64) {
        int v = (base + t < nb) ? bsum[base + t] : 0;
#pragma unroll
        for (int off = 1; off < 64; off <<= 1) {
            int y = __shfl_up(v, off);
            if (t >= off) v += y;
        }
        int c = carry;
        __syncthreads();
        if (base + t < nb) bsum[base + t] = v + c;
        if (t == 63) carry = c + v;
        __syncthreads();
    }
}

// Phase C: add exclusive block offset; rowptr[0] = 0.
__global__ __launch_bounds__(256) void scan_add(
    int* __restrict__ rowptr, const int* __restrict__ bsum, int n)
{
    int b = blockIdx.x, t = threadIdx.x;
    if (b == 0 && t == 0) rowptr[0] = 0;
    int ofs = (b == 0) ? 0 : bsum[b - 1];
    if (ofs == 0) return;
    int idx = b * 1024 + t * 4 + 1;
#pragma unroll
    for (int k = 0; k < 4; ++k)
        if (idx + k <= n) rowptr[idx + k] += ofs;
}

// stores SOURCE node index grouped by destination
__global__ void scatter_edges(const int* __restrict__ dst,
                              const int* __restrict__ src,
                              const int* __restrict__ rowptr,
                              int* __restrict__ cursor,
                              int* __restrict__ slist, int E)
{
    int t = blockIdx.x * blockDim.x + threadIdx.x;
    if (t < E) {
        int d = dst[t];
        int p = rowptr[d] + atomicAdd(&cursor[d], 1);
        slist[p] = src[t];
    }
}

// ----------- fused logits + ONLINE softmax + aggregate (single pass) -------
// wave per dst node; lane holds channels (2*lane, 2*lane+1); head = lane>>3.
// h is bf16 packed pairs. Output x packed bf16. Branchless online rescale.
__global__ __launch_bounds__(256) void aggregate(
    const unsigned int* __restrict__ Hm,
    const int* __restrict__ rowptr, const int* __restrict__ slist,
    const float* __restrict__ att, const float* __restrict__ bias,
    unsigned int* __restrict__ Outv, int n)
{
    int wid  = threadIdx.x >> 6;
    int lane = threadIdx.x & 63;
    int d = blockIdx.x * 4 + wid;
    if (d >= n) return;

    int beg = rowptr[d];
    int end = rowptr[d + 1];

    unsigned int ud = Hm[(size_t)d * 64 + lane];
    float hdx = bf2f(ud & 0xffffu), hdy = bf2f(ud >> 16);
    float2 aw = reinterpret_cast<const float2*>(att)[lane];

    float m = -3.4e38f, ssum = 0.f, accx = 0.f, accy = 0.f;

    int i = beg;
    for (; i + 1 < end; i += 2) {
        int s0 = slist[i];
        int s1 = slist[i + 1];
        unsigned int u0 = Hm[(size_t)s0 * 64 + lane];
        unsigned int u1 = Hm[(size_t)s1 * 64 + lane];
        float h0x = bf2f(u0 & 0xffffu), h0y = bf2f(u0 >> 16);
        float h1x = bf2f(u1 & 0xffffu), h1y = bf2f(u1 >> 16);

        float a0 = h0x + hdx; a0 = a0 > 0.f ? a0 : 0.2f * a0;
        float b0 = h0y + hdy; b0 = b0 > 0.f ? b0 : 0.2f * b0;
        float p0 = a0 * aw.x + b0 * aw.y;
        float a1 = h1x + hdx; a1 = a1 > 0.f ? a1 : 0.2f * a1;
        float b1 = h1y + hdy; b1 = b1 > 0.f ? b1 : 0.2f * b1;
        float p1 = a1 * aw.x + b1 * aw.y;
        p0 += __shfl_xor(p0, 1); p0 += __shfl_xor(p0, 2); p0 += __shfl_xor(p0, 4);
        p1 += __shfl_xor(p1, 1); p1 += __shfl_xor(p1, 2); p1 += __shfl_xor(p1, 4);

        float mn = fmaxf(m, fmaxf(p0, p1));
        float sc = expf(m - mn);            // m==-inf first time -> 0
        float e0 = expf(p0 - mn);
        float e1 = expf(p1 - mn);
        ssum = ssum * sc + e0 + e1;
        accx = accx * sc + e0 * h0x + e1 * h1x;
        accy = accy * sc + e0 * h0y + e1 * h1y;
        m = mn;
    }
    if (i < end) {
        int s0 = slist[i];
        unsigned int u0 = Hm[(size_t)s0 * 64 + lane];
        float h0x = bf2f(u0 & 0xffffu), h0y = bf2f(u0 >> 16);
        float a0 = h0x + hdx; a0 = a0 > 0.f ? a0 : 0.2f * a0;
        float b0 = h0y + hdy; b0 = b0 > 0.f ? b0 : 0.2f * b0;
        float p0 = a0 * aw.x + b0 * aw.y;
        p0 += __shfl_xor(p0, 1); p0 += __shfl_xor(p0, 2); p0 += __shfl_xor(p0, 4);
        float mn = fmaxf(m, p0);
        float sc = expf(m - mn);
        float e0 = expf(p0 - mn);
        ssum = ssum * sc + e0;
        accx = accx * sc + e0 * h0x;
        accy = accy * sc + e0 * h0y;
        m = mn;
    }

    float inv = 1.f / (ssum + 1e-16f);
    float2 bv = reinterpret_cast<const float2*>(bias)[lane];
    float ox = accx * inv + bv.x;
    float oy = accy * inv + bv.y;
    Outv[(size_t)d * 64 + lane] =
        (unsigned int)f2bf(ox) | ((unsigned int)f2bf(oy) << 16);
}

// ------------------------------ LayerNorm ----------------------------------
__global__ __launch_bounds__(256) void ln_kernel(
    const float* __restrict__ Y, const float* __restrict__ g,
    const float* __restrict__ b, float* __restrict__ Out, int n)
{
    int wid  = threadIdx.x >> 6;
    int lane = threadIdx.x & 63;
    int r = blockIdx.x * 4 + wid;
    if (r >= n) return;

    float2 v = reinterpret_cast<const float2*>(Y)[(size_t)r * 64 + lane];
    float sum = v.x + v.y;
#pragma unroll
    for (int off = 32; off >= 1; off >>= 1) sum += __shfl_xor(sum, off);
    float mu = sum * (1.f / 128.f);
    float dx = v.x - mu, dy = v.y - mu;
    float sq = dx * dx + dy * dy;
#pragma unroll
    for (int off = 32; off >= 1; off >>= 1) sq += __shfl_xor(sq, off);
    float inv = rsqrtf(sq * (1.f / 128.f) + 1e-12f);
    float2 gv = reinterpret_cast<const float2*>(g)[lane];
    float2 bv = reinterpret_cast<const float2*>(b)[lane];
    float2 o;
    o.x = dx * inv * gv.x + bv.x;
    o.y = dy * inv * gv.y + bv.y;
    reinterpret_cast<float2*>(Out)[(size_t)r * 64 + lane] = o;
}

// ---------------------------------------------------------------------------
extern "C" void kernel_launch(void* const* d_in, const int* in_sizes, int n_in,
                              void* d_out, int out_size, void* d_ws, size_t ws_size,
                              hipStream_t stream)
{
    const float* x    = (const float*)d_in[0];
    const int*   edge = (const int*)d_in[1];     // int32 (harness converts int64)
    const float* W    = (const float*)d_in[2];
    const float* att  = (const float*)d_in[3];
    const float* bias = (const float*)d_in[4];
    const float* outW = (const float*)d_in[5];
    const float* outb = (const float*)d_in[6];
    const float* lng  = (const float*)d_in[7];
    const float* lnb  = (const float*)d_in[8];

    const int N  = in_sizes[0] / D;
    const int E  = in_sizes[1] / 2;
    const int NT = out_size / D;

    const int* srcp = edge;
    const int* dstp = edge + E;

    auto align256 = [](size_t v) { return (v + 255) & ~(size_t)255; };
    auto cdiv = [](int a, int b) { return (a + b - 1) / b; };

    const int NB = cdiv(N, 1024);    // scan blocks

    // ws carve: h/y union, rowptr, cnt, slist, bsum  (~16.5 MB)
    size_t ybytes = (size_t)NT * D * 4;
    size_t hb     = (size_t)N * D * 2;
    size_t hbytes = align256(hb > ybytes ? hb : ybytes);

    char* wp = (char*)d_ws;
    size_t off = 0;
    void* hbuf   = (void*)(wp + off); off += hbytes;
    int*  rowptr = (int*)(wp + off);  off += align256((size_t)(N + 1) * 4);
    int*  cnt    = (int*)(wp + off);  off += align256((size_t)N * 4);
    int*  slist  = (int*)(wp + off);  off += align256((size_t)E * 4);
    int*  bsum   = (int*)(wp + off);
    unsigned int* xb = (unsigned int*)d_out;   // bf16 activations in d_out
    float* ybuf = (float*)hbuf;                // head GEMM out reuses h buffer
    (void)n_in; (void)ws_size;

    // ---- CSR build ----
    zero_ints<<<cdiv(N, 256), 256, 0, stream>>>(cnt, N);
    count_edges<<<cdiv(E, 256), 256, 0, stream>>>(dstp, cnt, E);
    scan_blocks<<<NB, 256, 0, stream>>>(cnt, rowptr, bsum, N);
    scan_bsums<<<1, 64, 0, stream>>>(bsum, NB);
    scan_add<<<NB, 256, 0, stream>>>(rowptr, bsum, N);
    zero_ints<<<cdiv(N, 256), 256, 0, stream>>>(cnt, N);
    scatter_edges<<<cdiv(E, 256), 256, 0, stream>>>(dstp, srcp, rowptr, cnt, slist, E);

    // ---- layer 0: h = x @ W0 (f32 in, bf16 out) ----
    gemm128<0,1,0><<<cdiv(N, 64), 256, 0, stream>>>(x, W, nullptr, hbuf, N);
    aggregate<<<cdiv(N, 4), 256, 0, stream>>>((unsigned int*)hbuf, rowptr, slist,
                                              att, bias, xb, N);
    // ---- layer 1: h = gelu(x) @ W1 (bf16 in, bf16 out) ----
    gemm128<1,1,1><<<cdiv(N, 64), 256, 0, stream>>>(xb, W + D * D, nullptr, hbuf, N);
    aggregate<<<cdiv(N, 4), 256, 0, stream>>>((unsigned int*)hbuf, rowptr, slist,
                                              att + H * C, bias + D, xb, N);
    // ---- head: y = x @ outW + outb (bf16 in, f32 out), then LN ----
    gemm128<1,0,0><<<cdiv(NT, 64), 256, 0, stream>>>(xb, outW, outb, ybuf, NT);
    ln_kernel<<<cdiv(NT, 4), 256, 0, stream>>>(ybuf, lng, lnb, (float*)d_out, NT);
}

// Round 8
// 270.846 us; speedup vs baseline: 2.5467x; 1.3273x over previous
//
#include <hip/hip_runtime.h>
#include <math.h>

// ---------------------------------------------------------------------------
// GATv2 encoder. r7 profile: aggregate VALU-bound (86.6% VALUBusy, 15% HBM).
// This round: (1) aggregate v2 - 4-edge unroll, 32-bit addressing, 2-op
// leaky, __expf; (2) GEMMs moved to MFMA bf16 (16x16x32), W pre-transposed
// to bf16 once. x activations bf16 in d_out; h bf16 in ws.
// ---------------------------------------------------------------------------

#define D 128
#define H 8
#define C 16

typedef __attribute__((ext_vector_type(8))) short bf16x8v;
typedef __attribute__((ext_vector_type(4))) float f32x4v;

static __device__ __forceinline__ float bf2f(unsigned int u16) {
    union { unsigned int i; float f; } x; x.i = u16 << 16; return x.f;
}
static __device__ __forceinline__ unsigned short f2bf(float f) {
    union { float f; unsigned int i; } x; x.f = f;
    unsigned int r = x.i + 0x7fffu + ((x.i >> 16) & 1u);   // RNE
    return (unsigned short)(r >> 16);
}
static __device__ __forceinline__ float gelu_f(float v) {
    return 0.5f * v * (1.0f + erff(v * 0.70710678118654752f));
}

// ---------------- W transpose+cast: Wt[n][k] bf16 from W[k][n] f32 ----------
// block b: 0,1 -> W+b*16384 ; 2 -> outW. dst wbf + b*16384.
__global__ __launch_bounds__(256) void transpose_w(
    const float* __restrict__ W, const float* __restrict__ outW,
    unsigned short* __restrict__ wbf)
{
    int b = blockIdx.x, t = threadIdx.x;
    const float* src = (b < 2) ? (W + (size_t)b * D * D) : outW;
    unsigned short* dst = wbf + (size_t)b * D * D;
#pragma unroll
    for (int i = 0; i < 64; ++i) {
        int idx = i * 256 + t;          // 0..16383
        int k = idx >> 7, n = idx & 127;
        dst[n * D + k] = f2bf(src[idx]);
    }
}

// ----------------------------- MFMA GEMM -----------------------------------
// Out[nrows x 128] = act(X[nrows x 128]) @ W[128 x 128] (+ bias)
// Wt: bf16, transposed [n][k]. Block: 256 thr = 4 waves; 64 rows/block.
// LDS layouts (k-chunk-major, c = k/8):
//   Alds[c][row][8]  (rows padded to 65)   Wlds[ck][col][8] (cols padded 129)
// Frag (16x16x32 bf16): lane l: row/col = l&15, k = (l>>4)*8 + j.
template<int IN_BF, int OUT_BF, int GELU>
__global__ __launch_bounds__(256) void gemm_mfma(
    const void* __restrict__ Xv, const unsigned short* __restrict__ Wt,
    const float* __restrict__ bias, void* __restrict__ Outv, int nrows)
{
    __shared__ short Alds[16][65][8];
    __shared__ short Wlds[16][129][8];

    const int t  = threadIdx.x;
    const int m0 = blockIdx.x * 64;

    // ---- stage A: 1024 cells (r,c), c-fast for coalesced global reads ----
#pragma unroll
    for (int w = 0; w < 4; ++w) {
        int cell = w * 256 + t;
        int c = cell & 15, r = cell >> 4;
        float v[8];
        if (m0 + r < nrows) {
            if (IN_BF) {
                uint4 q = reinterpret_cast<const uint4*>(Xv)[(size_t)(m0 + r) * 16 + c];
                unsigned int qq[4] = {q.x, q.y, q.z, q.w};
#pragma unroll
                for (int j = 0; j < 4; ++j) {
                    v[2 * j]     = bf2f(qq[j] & 0xffffu);
                    v[2 * j + 1] = bf2f(qq[j] >> 16);
                }
            } else {
                float4 a = reinterpret_cast<const float4*>(Xv)[(size_t)(m0 + r) * 32 + c * 2];
                float4 b = reinterpret_cast<const float4*>(Xv)[(size_t)(m0 + r) * 32 + c * 2 + 1];
                v[0] = a.x; v[1] = a.y; v[2] = a.z; v[3] = a.w;
                v[4] = b.x; v[5] = b.y; v[6] = b.z; v[7] = b.w;
            }
            if (GELU) {
#pragma unroll
                for (int j = 0; j < 8; ++j) v[j] = gelu_f(v[j]);
            }
        } else {
#pragma unroll
            for (int j = 0; j < 8; ++j) v[j] = 0.f;
        }
        short pk[8];
#pragma unroll
        for (int j = 0; j < 8; ++j) pk[j] = (short)f2bf(v[j]);
        *reinterpret_cast<uint4*>(&Alds[c][r][0]) = *reinterpret_cast<uint4*>(pk);
    }

    // ---- stage W: 2048 cells (col, ck), ck-fast; Wt row = 256B contiguous --
#pragma unroll
    for (int w = 0; w < 8; ++w) {
        int cell = w * 256 + t;
        int col = cell >> 4, ck = cell & 15;
        uint4 q = reinterpret_cast<const uint4*>(Wt)[col * 16 + ck];
        *reinterpret_cast<uint4*>(&Wlds[ck][col][0]) = q;
    }
    __syncthreads();

    // ---- MFMA: wave wv does rows wv*16..wv*16+15, all 8 col tiles ----------
    const int l  = t & 63;
    const int wv = t >> 6;
    const int g  = l >> 4;       // k-subgroup
    const int r  = l & 15;       // frag row/col index

    f32x4v acc[8];
#pragma unroll
    for (int ct = 0; ct < 8; ++ct) acc[ct] = (f32x4v){0.f, 0.f, 0.f, 0.f};

#pragma unroll
    for (int kk = 0; kk < 4; ++kk) {
        bf16x8v a = *reinterpret_cast<const bf16x8v*>(&Alds[kk * 4 + g][wv * 16 + r][0]);
#pragma unroll
        for (int ct = 0; ct < 8; ++ct) {
            bf16x8v b = *reinterpret_cast<const bf16x8v*>(&Wlds[kk * 4 + g][ct * 16 + r][0]);
            acc[ct] = __builtin_amdgcn_mfma_f32_16x16x32_bf16(a, b, acc[ct], 0, 0, 0);
        }
    }

    // ---- epilogue: D row = g*4+i (in-tile), col = ct*16+r ------------------
#pragma unroll
    for (int ct = 0; ct < 8; ++ct) {
        int col = ct * 16 + r;
        float bj = bias ? bias[col] : 0.f;
#pragma unroll
        for (int i = 0; i < 4; ++i) {
            int rr = m0 + wv * 16 + g * 4 + i;
            if (rr < nrows) {
                float val = acc[ct][i] + bj;
                if (OUT_BF)
                    reinterpret_cast<unsigned short*>(Outv)[(size_t)rr * 128 + col] = f2bf(val);
                else
                    reinterpret_cast<float*>(Outv)[(size_t)rr * 128 + col] = val;
            }
        }
    }
}

// ------------------------- CSR build kernels -------------------------------
__global__ void zero_ints(int* __restrict__ p, int n)
{
    int stride = gridDim.x * blockDim.x;
    for (int i = blockIdx.x * blockDim.x + threadIdx.x; i < n; i += stride) p[i] = 0;
}

__global__ void count_edges(const int* __restrict__ dst, int* __restrict__ cnt, int E)
{
    int t = blockIdx.x * blockDim.x + threadIdx.x;
    if (t < E) atomicAdd(&cnt[dst[t]], 1);
}

__global__ __launch_bounds__(256) void scan_blocks(
    const int* __restrict__ cnt, int* __restrict__ rowptr,
    int* __restrict__ bsum, int n)
{
    __shared__ int sh[256];
    const int b = blockIdx.x, t = threadIdx.x;
    const int base = b * 1024 + t * 4;
    int v0 = 0, v1 = 0, v2 = 0, v3 = 0;
    if (base + 3 < n) {
        int4 q = *reinterpret_cast<const int4*>(cnt + base);
        v0 = q.x; v1 = q.y; v2 = q.z; v3 = q.w;
    } else {
        if (base     < n) v0 = cnt[base];
        if (base + 1 < n) v1 = cnt[base + 1];
        if (base + 2 < n) v2 = cnt[base + 2];
        if (base + 3 < n) v3 = cnt[base + 3];
    }
    int s = v0 + v1 + v2 + v3;
    sh[t] = s;
    __syncthreads();
#pragma unroll
    for (int off = 1; off < 256; off <<= 1) {
        int x = (t >= off) ? sh[t - off] : 0;
        __syncthreads();
        sh[t] += x;
        __syncthreads();
    }
    int excl = sh[t] - s;
    int p0 = excl + v0, p1 = p0 + v1, p2 = p1 + v2, p3 = p2 + v3;
    if (base     < n) rowptr[base + 1] = p0;
    if (base + 1 < n) rowptr[base + 2] = p1;
    if (base + 2 < n) rowptr[base + 3] = p2;
    if (base + 3 < n) rowptr[base + 4] = p3;
    if (t == 255) bsum[b] = sh[255];
}

__global__ void scan_bsums(int* __restrict__ bsum, int nb)
{
    __shared__ int carry;
    int t = threadIdx.x & 63;
    if (threadIdx.x == 0) carry = 0;
    __syncthreads();
    for (int base = 0; base < nb; base += 64) {
        int v = (base + t < nb) ? bsum[base + t] : 0;
#pragma unroll
        for (int off = 1; off < 64; off <<= 1) {
            int y = __shfl_up(v, off);
            if (t >= off) v += y;
        }
        int c = carry;
        __syncthreads();
        if (base + t < nb) bsum[base + t] = v + c;
        if (t == 63) carry = c + v;
        __syncthreads();
    }
}

__global__ __launch_bounds__(256) void scan_add(
    int* __restrict__ rowptr, const int* __restrict__ bsum, int n)
{
    int b = blockIdx.x, t = threadIdx.x;
    if (b == 0 && t == 0) rowptr[0] = 0;
    int ofs = (b == 0) ? 0 : bsum[b - 1];
    if (ofs == 0) return;
    int idx = b * 1024 + t * 4 + 1;
#pragma unroll
    for (int k = 0; k < 4; ++k)
        if (idx + k <= n) rowptr[idx + k] += ofs;
}

__global__ void scatter_edges(const int* __restrict__ dst,
                              const int* __restrict__ src,
                              const int* __restrict__ rowptr,
                              int* __restrict__ cursor,
                              int* __restrict__ slist, int E)
{
    int t = blockIdx.x * blockDim.x + threadIdx.x;
    if (t < E) {
        int d = dst[t];
        int p = rowptr[d] + atomicAdd(&cursor[d], 1);
        slist[p] = src[t];
    }
}

// ----------- fused logits + ONLINE softmax + aggregate (4-edge unroll) -----
// wave per dst node; lane = channels (2*lane,2*lane+1); head = lane>>3.
#define EDGE_PRE(k) \
    unsigned int u##k = Hm[((unsigned)s##k << 6) | lane]; \
    float h##k##x = bf2f(u##k & 0xffffu), h##k##y = bf2f(u##k >> 16); \
    float a##k = h##k##x + hdx; a##k = fmaxf(a##k, 0.2f * a##k); \
    float b##k = h##k##y + hdy; b##k = fmaxf(b##k, 0.2f * b##k); \
    float p##k = a##k * aw.x + b##k * aw.y; \
    p##k += __shfl_xor(p##k, 1); p##k += __shfl_xor(p##k, 2); p##k += __shfl_xor(p##k, 4);

__global__ __launch_bounds__(256) void aggregate(
    const unsigned int* __restrict__ Hm,
    const int* __restrict__ rowptr, const int* __restrict__ slist,
    const float* __restrict__ att, const float* __restrict__ bias,
    unsigned int* __restrict__ Outv, int n)
{
    int wid  = threadIdx.x >> 6;
    int lane = threadIdx.x & 63;
    int d = blockIdx.x * 4 + wid;
    if (d >= n) return;

    int beg = rowptr[d];
    int end = rowptr[d + 1];

    unsigned int ud = Hm[((unsigned)d << 6) | lane];
    float hdx = bf2f(ud & 0xffffu), hdy = bf2f(ud >> 16);
    float2 aw = reinterpret_cast<const float2*>(att)[lane];

    float m = -3.4e38f, ssum = 0.f, accx = 0.f, accy = 0.f;

    int i = beg;
    for (; i + 3 < end; i += 4) {
        int s0 = slist[i], s1 = slist[i + 1], s2 = slist[i + 2], s3 = slist[i + 3];
        EDGE_PRE(0) EDGE_PRE(1) EDGE_PRE(2) EDGE_PRE(3)
        float mx = fmaxf(fmaxf(p0, p1), fmaxf(p2, p3));
        float mn = fmaxf(m, mx);
        float sc = __expf(m - mn);
        float e0 = __expf(p0 - mn), e1 = __expf(p1 - mn);
        float e2 = __expf(p2 - mn), e3 = __expf(p3 - mn);
        ssum = fmaf(ssum, sc, (e0 + e1) + (e2 + e3));
        accx = fmaf(accx, sc, fmaf(e0, h0x, fmaf(e1, h1x, fmaf(e2, h2x, e3 * h3x))));
        accy = fmaf(accy, sc, fmaf(e0, h0y, fmaf(e1, h1y, fmaf(e2, h2y, e3 * h3y))));
        m = mn;
    }
    for (; i < end; ++i) {
        int s0 = slist[i];
        EDGE_PRE(0)
        float mn = fmaxf(m, p0);
        float sc = __expf(m - mn);
        float e0 = __expf(p0 - mn);
        ssum = fmaf(ssum, sc, e0);
        accx = fmaf(accx, sc, e0 * h0x);
        accy = fmaf(accy, sc, e0 * h0y);
        m = mn;
    }

    float inv = 1.f / (ssum + 1e-16f);
    float2 bv = reinterpret_cast<const float2*>(bias)[lane];
    float ox = accx * inv + bv.x;
    float oy = accy * inv + bv.y;
    Outv[((unsigned)d << 6) | lane] =
        (unsigned int)f2bf(ox) | ((unsigned int)f2bf(oy) << 16);
}

// ------------------------------ LayerNorm ----------------------------------
__global__ __launch_bounds__(256) void ln_kernel(
    const float* __restrict__ Y, const float* __restrict__ g,
    const float* __restrict__ b, float* __restrict__ Out, int n)
{
    int wid  = threadIdx.x >> 6;
    int lane = threadIdx.x & 63;
    int r = blockIdx.x * 4 + wid;
    if (r >= n) return;

    float2 v = reinterpret_cast<const float2*>(Y)[(size_t)r * 64 + lane];
    float sum = v.x + v.y;
#pragma unroll
    for (int off = 32; off >= 1; off >>= 1) sum += __shfl_xor(sum, off);
    float mu = sum * (1.f / 128.f);
    float dx = v.x - mu, dy = v.y - mu;
    float sq = dx * dx + dy * dy;
#pragma unroll
    for (int off = 32; off >= 1; off >>= 1) sq += __shfl_xor(sq, off);
    float inv = rsqrtf(sq * (1.f / 128.f) + 1e-12f);
    float2 gv = reinterpret_cast<const float2*>(g)[lane];
    float2 bv = reinterpret_cast<const float2*>(b)[lane];
    float2 o;
    o.x = dx * inv * gv.x + bv.x;
    o.y = dy * inv * gv.y + bv.y;
    reinterpret_cast<float2*>(Out)[(size_t)r * 64 + lane] = o;
}

// ---------------------------------------------------------------------------
extern "C" void kernel_launch(void* const* d_in, const int* in_sizes, int n_in,
                              void* d_out, int out_size, void* d_ws, size_t ws_size,
                              hipStream_t stream)
{
    const float* x    = (const float*)d_in[0];
    const int*   edge = (const int*)d_in[1];     // int32 (harness converts int64)
    const float* W    = (const float*)d_in[2];
    const float* att  = (const float*)d_in[3];
    const float* bias = (const float*)d_in[4];
    const float* outW = (const float*)d_in[5];
    const float* outb = (const float*)d_in[6];
    const float* lng  = (const float*)d_in[7];
    const float* lnb  = (const float*)d_in[8];

    const int N  = in_sizes[0] / D;
    const int E  = in_sizes[1] / 2;
    const int NT = out_size / D;

    const int* srcp = edge;
    const int* dstp = edge + E;

    auto align256 = [](size_t v) { return (v + 255) & ~(size_t)255; };
    auto cdiv = [](int a, int b) { return (a + b - 1) / b; };

    const int NB = cdiv(N, 1024);    // scan blocks

    // ws carve: h/y union, wbf (3x128x128 bf16), rowptr, cnt, slist, bsum
    size_t ybytes = (size_t)NT * D * 4;
    size_t hb     = (size_t)N * D * 2;
    size_t hbytes = align256(hb > ybytes ? hb : ybytes);

    char* wp = (char*)d_ws;
    size_t off = 0;
    void* hbuf   = (void*)(wp + off); off += hbytes;
    unsigned short* wbf = (unsigned short*)(wp + off); off += align256((size_t)3 * D * D * 2);
    int*  rowptr = (int*)(wp + off);  off += align256((size_t)(N + 1) * 4);
    int*  cnt    = (int*)(wp + off);  off += align256((size_t)N * 4);
    int*  slist  = (int*)(wp + off);  off += align256((size_t)E * 4);
    int*  bsum   = (int*)(wp + off);
    unsigned int* xb = (unsigned int*)d_out;   // bf16 activations in d_out
    float* ybuf = (float*)hbuf;                // head GEMM out reuses h buffer
    (void)n_in; (void)ws_size;

    // ---- weight transpose+cast (once) ----
    transpose_w<<<3, 256, 0, stream>>>(W, outW, wbf);

    // ---- CSR build ----
    zero_ints<<<cdiv(N, 256), 256, 0, stream>>>(cnt, N);
    count_edges<<<cdiv(E, 256), 256, 0, stream>>>(dstp, cnt, E);
    scan_blocks<<<NB, 256, 0, stream>>>(cnt, rowptr, bsum, N);
    scan_bsums<<<1, 64, 0, stream>>>(bsum, NB);
    scan_add<<<NB, 256, 0, stream>>>(rowptr, bsum, N);
    zero_ints<<<cdiv(N, 256), 256, 0, stream>>>(cnt, N);
    scatter_edges<<<cdiv(E, 256), 256, 0, stream>>>(dstp, srcp, rowptr, cnt, slist, E);

    // ---- layer 0: h = x @ W0 (f32 in, bf16 out) ----
    gemm_mfma<0,1,0><<<cdiv(N, 64), 256, 0, stream>>>(x, wbf, nullptr, hbuf, N);
    aggregate<<<cdiv(N, 4), 256, 0, stream>>>((unsigned int*)hbuf, rowptr, slist,
                                              att, bias, xb, N);
    // ---- layer 1: h = gelu(x) @ W1 (bf16 in, bf16 out) ----
    gemm_mfma<1,1,1><<<cdiv(N, 64), 256, 0, stream>>>(xb, wbf + D * D, nullptr, hbuf, N);
    aggregate<<<cdiv(N, 4), 256, 0, stream>>>((unsigned int*)hbuf, rowptr, slist,
                                              att + H * C, bias + D, xb, N);
    // ---- head: y = x @ outW + outb (bf16 in, f32 out), then LN ----
    gemm_mfma<1,0,0><<<cdiv(NT, 64), 256, 0, stream>>>(xb, wbf + 2 * D * D, outb, ybuf, NT);
    ln_kernel<<<cdiv(NT, 4), 256, 0, stream>>>(ybuf, lng, lnb, (float*)d_out, NT);
}

// Round 9
// 261.684 us; speedup vs baseline: 2.6358x; 1.0350x over previous
//
#include <hip/hip_runtime.h>
#include <math.h>

// ---------------------------------------------------------------------------
// GATv2 encoder. r8: aggregate 52us VALU-bound w/ 3 ds_swizzle per edge ->
// replace with DPP-add reduce (quad_perm xor1/xor2 + row_half_mirror).
// GEMM was LDS-conflict-bound -> A direct global->VGPR (no reuse), W in
// XOR-swizzled LDS (2-way = free).
// ---------------------------------------------------------------------------

#define D 128
#define H 8
#define C 16

typedef __attribute__((ext_vector_type(8))) short bf16x8v;
typedef __attribute__((ext_vector_type(4))) float f32x4v;

static __device__ __forceinline__ float bf2f(unsigned int u16) {
    union { unsigned int i; float f; } x; x.i = u16 << 16; return x.f;
}
static __device__ __forceinline__ unsigned short f2bf(float f) {
    union { float f; unsigned int i; } x; x.f = f;
    unsigned int r = x.i + 0x7fffu + ((x.i >> 16) & 1u);   // RNE
    return (unsigned short)(r >> 16);
}
static __device__ __forceinline__ float gelu_f(float v) {
    return 0.5f * v * (1.0f + erff(v * 0.70710678118654752f));
}
// DPP-powered cross-lane add: v += lane[ctrl-permuted]
#define DPP_ADD(v, ctrl) \
    (v) += __builtin_bit_cast(float, __builtin_amdgcn_update_dpp( \
        0, __builtin_bit_cast(int, (v)), (ctrl), 0xf, 0xf, true))

// ---------------- W transpose+cast: Wt[n][k] bf16 from W[k][n] f32 ----------
__global__ __launch_bounds__(256) void transpose_w(
    const float* __restrict__ W, const float* __restrict__ outW,
    unsigned short* __restrict__ wbf)
{
    int b = blockIdx.x, t = threadIdx.x;
    const float* src = (b < 2) ? (W + (size_t)b * D * D) : outW;
    unsigned short* dst = wbf + (size_t)b * D * D;
#pragma unroll
    for (int i = 0; i < 64; ++i) {
        int idx = i * 256 + t;          // 0..16383
        int k = idx >> 7, n = idx & 127;
        dst[n * D + k] = f2bf(src[idx]);
    }
}

// ----------------------------- MFMA GEMM -----------------------------------
// Out[nrows x 128] = act(X[nrows x 128]) @ W (+bias).  Wt bf16 [n][k].
// 256 thr = 4 waves, 64 rows/block. A-frags: direct global->VGPR (no LDS;
// rows have no cross-wave reuse). W: LDS, XOR-swizzled 16B units:
// unit = col*16 + (kg ^ (col&7))  -> reads & writes 2-way (free).
// Frag (16x16x32): lane l: row/col=l&15, kg_intile=l>>4; kg = kk*4 + (l>>4).
template<int IN_BF, int OUT_BF, int GELU>
__global__ __launch_bounds__(256) void gemm_mfma(
    const void* __restrict__ Xv, const unsigned short* __restrict__ Wt,
    const float* __restrict__ bias, void* __restrict__ Outv, int nrows)
{
    __shared__ short Wlds[128 * 128];   // 32 KB

    const int t  = threadIdx.x;
    const int m0 = blockIdx.x * 64;

    // ---- stage W: 2048 16B-cells (col, kg) ----
#pragma unroll
    for (int w = 0; w < 8; ++w) {
        int cell = w * 256 + t;
        int col = cell >> 4, kg = cell & 15;
        uint4 q = reinterpret_cast<const uint4*>(Wt)[col * 16 + kg];
        *reinterpret_cast<uint4*>(&Wlds[(col * 16 + (kg ^ (col & 7))) * 8]) = q;
    }

    const int l  = t & 63;
    const int wv = t >> 6;
    const int g  = l >> 4;       // in-tile k-subgroup 0..3
    const int r  = l & 15;       // frag row/col
    const int row = m0 + wv * 16 + r;
    const bool rv = row < nrows;

    // ---- A frags: direct global loads ----
    bf16x8v afrag[4];
#pragma unroll
    for (int kk = 0; kk < 4; ++kk) {
        int kg = kk * 4 + g;
        float v[8];
        if (IN_BF) {
            uint4 q = make_uint4(0, 0, 0, 0);
            if (rv) q = reinterpret_cast<const uint4*>(Xv)[(size_t)row * 16 + kg];
            if (GELU) {
                unsigned int qq[4] = {q.x, q.y, q.z, q.w};
#pragma unroll
                for (int j = 0; j < 4; ++j) {
                    v[2 * j]     = gelu_f(bf2f(qq[j] & 0xffffu));
                    v[2 * j + 1] = gelu_f(bf2f(qq[j] >> 16));
                }
                short pk[8];
#pragma unroll
                for (int j = 0; j < 8; ++j) pk[j] = (short)f2bf(v[j]);
                afrag[kk] = *reinterpret_cast<bf16x8v*>(pk);
            } else {
                afrag[kk] = __builtin_bit_cast(bf16x8v, q);
            }
        } else {
            float4 a = make_float4(0.f, 0.f, 0.f, 0.f), b = a;
            if (rv) {
                a = reinterpret_cast<const float4*>(Xv)[(size_t)row * 32 + kg * 2];
                b = reinterpret_cast<const float4*>(Xv)[(size_t)row * 32 + kg * 2 + 1];
            }
            v[0] = a.x; v[1] = a.y; v[2] = a.z; v[3] = a.w;
            v[4] = b.x; v[5] = b.y; v[6] = b.z; v[7] = b.w;
            if (GELU) {
#pragma unroll
                for (int j = 0; j < 8; ++j) v[j] = gelu_f(v[j]);
            }
            short pk[8];
#pragma unroll
            for (int j = 0; j < 8; ++j) pk[j] = (short)f2bf(v[j]);
            afrag[kk] = *reinterpret_cast<bf16x8v*>(pk);
        }
    }
    __syncthreads();

    // ---- MFMA main: 4 kk x 8 ct ----
    f32x4v acc[8];
#pragma unroll
    for (int ct = 0; ct < 8; ++ct) acc[ct] = (f32x4v){0.f, 0.f, 0.f, 0.f};

#pragma unroll
    for (int kk = 0; kk < 4; ++kk) {
        int kg = kk * 4 + g;
#pragma unroll
        for (int ct = 0; ct < 8; ++ct) {
            int col = ct * 16 + r;
            bf16x8v b = *reinterpret_cast<const bf16x8v*>(
                &Wlds[(col * 16 + (kg ^ (col & 7))) * 8]);
            acc[ct] = __builtin_amdgcn_mfma_f32_16x16x32_bf16(afrag[kk], b, acc[ct], 0, 0, 0);
        }
    }

    // ---- epilogue: D row = g*4+i, col = ct*16+r ----
#pragma unroll
    for (int ct = 0; ct < 8; ++ct) {
        int col = ct * 16 + r;
        float bj = bias ? bias[col] : 0.f;
#pragma unroll
        for (int i = 0; i < 4; ++i) {
            int rr = m0 + wv * 16 + g * 4 + i;
            if (rr < nrows) {
                float val = acc[ct][i] + bj;
                if (OUT_BF)
                    reinterpret_cast<unsigned short*>(Outv)[(size_t)rr * 128 + col] = f2bf(val);
                else
                    reinterpret_cast<float*>(Outv)[(size_t)rr * 128 + col] = val;
            }
        }
    }
}

// ------------------------- CSR build kernels -------------------------------
__global__ void zero_ints(int* __restrict__ p, int n)
{
    int stride = gridDim.x * blockDim.x;
    for (int i = blockIdx.x * blockDim.x + threadIdx.x; i < n; i += stride) p[i] = 0;
}

__global__ void count_edges(const int* __restrict__ dst, int* __restrict__ cnt, int E)
{
    int t = blockIdx.x * blockDim.x + threadIdx.x;
    if (t < E) atomicAdd(&cnt[dst[t]], 1);
}

__global__ __launch_bounds__(256) void scan_blocks(
    const int* __restrict__ cnt, int* __restrict__ rowptr,
    int* __restrict__ bsum, int n)
{
    __shared__ int sh[256];
    const int b = blockIdx.x, t = threadIdx.x;
    const int base = b * 1024 + t * 4;
    int v0 = 0, v1 = 0, v2 = 0, v3 = 0;
    if (base + 3 < n) {
        int4 q = *reinterpret_cast<const int4*>(cnt + base);
        v0 = q.x; v1 = q.y; v2 = q.z; v3 = q.w;
    } else {
        if (base     < n) v0 = cnt[base];
        if (base + 1 < n) v1 = cnt[base + 1];
        if (base + 2 < n) v2 = cnt[base + 2];
        if (base + 3 < n) v3 = cnt[base + 3];
    }
    int s = v0 + v1 + v2 + v3;
    sh[t] = s;
    __syncthreads();
#pragma unroll
    for (int off = 1; off < 256; off <<= 1) {
        int x = (t >= off) ? sh[t - off] : 0;
        __syncthreads();
        sh[t] += x;
        __syncthreads();
    }
    int excl = sh[t] - s;
    int p0 = excl + v0, p1 = p0 + v1, p2 = p1 + v2, p3 = p2 + v3;
    if (base     < n) rowptr[base + 1] = p0;
    if (base + 1 < n) rowptr[base + 2] = p1;
    if (base + 2 < n) rowptr[base + 3] = p2;
    if (base + 3 < n) rowptr[base + 4] = p3;
    if (t == 255) bsum[b] = sh[255];
}

__global__ void scan_bsums(int* __restrict__ bsum, int nb)
{
    __shared__ int carry;
    int t = threadIdx.x & 63;
    if (threadIdx.x == 0) carry = 0;
    __syncthreads();
    for (int base = 0; base < nb; base += 64) {
        int v = (base + t < nb) ? bsum[base + t] : 0;
#pragma unroll
        for (int off = 1; off < 64; off <<= 1) {
            int y = __shfl_up(v, off);
            if (t >= off) v += y;
        }
        int c = carry;
        __syncthreads();
        if (base + t < nb) bsum[base + t] = v + c;
        if (t == 63) carry = c + v;
        __syncthreads();
    }
}

__global__ __launch_bounds__(256) void scan_add(
    int* __restrict__ rowptr, const int* __restrict__ bsum, int n)
{
    int b = blockIdx.x, t = threadIdx.x;
    if (b == 0 && t == 0) rowptr[0] = 0;
    int ofs = (b == 0) ? 0 : bsum[b - 1];
    if (ofs == 0) return;
    int idx = b * 1024 + t * 4 + 1;
#pragma unroll
    for (int k = 0; k < 4; ++k)
        if (idx + k <= n) rowptr[idx + k] += ofs;
}

__global__ void scatter_edges(const int* __restrict__ dst,
                              const int* __restrict__ src,
                              const int* __restrict__ rowptr,
                              int* __restrict__ cursor,
                              int* __restrict__ slist, int E)
{
    int t = blockIdx.x * blockDim.x + threadIdx.x;
    if (t < E) {
        int d = dst[t];
        int p = rowptr[d] + atomicAdd(&cursor[d], 1);
        slist[p] = src[t];
    }
}

// ----------- fused logits + ONLINE softmax + aggregate ---------------------
// wave per dst node; lane = channels (2*lane,2*lane+1); head = lane>>3.
// 8-lane head reduce via DPP adds: xor1 (quad_perm 0xB1), xor2 (0x4E),
// then row_half_mirror (0x141: lane^7 -> sibling quad) = full 8-lane sum.
#define EDGE_PRE(k) \
    unsigned int u##k = Hm[((unsigned)s##k << 6) | lane]; \
    float h##k##x = bf2f(u##k & 0xffffu), h##k##y = bf2f(u##k >> 16); \
    float a##k = h##k##x + hdx; a##k = fmaxf(a##k, 0.2f * a##k); \
    float b##k = h##k##y + hdy; b##k = fmaxf(b##k, 0.2f * b##k); \
    float p##k = a##k * aw.x + b##k * aw.y; \
    DPP_ADD(p##k, 0xB1); DPP_ADD(p##k, 0x4E); DPP_ADD(p##k, 0x141);

__global__ __launch_bounds__(256) void aggregate(
    const unsigned int* __restrict__ Hm,
    const int* __restrict__ rowptr, const int* __restrict__ slist,
    const float* __restrict__ att, const float* __restrict__ bias,
    unsigned int* __restrict__ Outv, int n)
{
    int wid  = threadIdx.x >> 6;
    int lane = threadIdx.x & 63;
    int d = blockIdx.x * 4 + wid;
    if (d >= n) return;

    int beg = rowptr[d];
    int end = rowptr[d + 1];

    unsigned int ud = Hm[((unsigned)d << 6) | lane];
    float hdx = bf2f(ud & 0xffffu), hdy = bf2f(ud >> 16);
    float2 aw = reinterpret_cast<const float2*>(att)[lane];

    float m = -3.4e38f, ssum = 0.f, accx = 0.f, accy = 0.f;

    int i = beg;
    for (; i + 3 < end; i += 4) {
        int s0 = slist[i], s1 = slist[i + 1], s2 = slist[i + 2], s3 = slist[i + 3];
        EDGE_PRE(0) EDGE_PRE(1) EDGE_PRE(2) EDGE_PRE(3)
        float mx = fmaxf(fmaxf(p0, p1), fmaxf(p2, p3));
        float mn = fmaxf(m, mx);
        float sc = __expf(m - mn);
        float e0 = __expf(p0 - mn), e1 = __expf(p1 - mn);
        float e2 = __expf(p2 - mn), e3 = __expf(p3 - mn);
        ssum = fmaf(ssum, sc, (e0 + e1) + (e2 + e3));
        accx = fmaf(accx, sc, fmaf(e0, h0x, fmaf(e1, h1x, fmaf(e2, h2x, e3 * h3x))));
        accy = fmaf(accy, sc, fmaf(e0, h0y, fmaf(e1, h1y, fmaf(e2, h2y, e3 * h3y))));
        m = mn;
    }
    for (; i < end; ++i) {
        int s0 = slist[i];
        EDGE_PRE(0)
        float mn = fmaxf(m, p0);
        float sc = __expf(m - mn);
        float e0 = __expf(p0 - mn);
        ssum = fmaf(ssum, sc, e0);
        accx = fmaf(accx, sc, e0 * h0x);
        accy = fmaf(accy, sc, e0 * h0y);
        m = mn;
    }

    float inv = 1.f / (ssum + 1e-16f);
    float2 bv = reinterpret_cast<const float2*>(bias)[lane];
    float ox = accx * inv + bv.x;
    float oy = accy * inv + bv.y;
    Outv[((unsigned)d << 6) | lane] =
        (unsigned int)f2bf(ox) | ((unsigned int)f2bf(oy) << 16);
}

// ------------------------------ LayerNorm ----------------------------------
__global__ __launch_bounds__(256) void ln_kernel(
    const float* __restrict__ Y, const float* __restrict__ g,
    const float* __restrict__ b, float* __restrict__ Out, int n)
{
    int wid  = threadIdx.x >> 6;
    int lane = threadIdx.x & 63;
    int r = blockIdx.x * 4 + wid;
    if (r >= n) return;

    float2 v = reinterpret_cast<const float2*>(Y)[(size_t)r * 64 + lane];
    float sum = v.x + v.y;
#pragma unroll
    for (int off = 32; off >= 1; off >>= 1) sum += __shfl_xor(sum, off);
    float mu = sum * (1.f / 128.f);
    float dx = v.x - mu, dy = v.y - mu;
    float sq = dx * dx + dy * dy;
#pragma unroll
    for (int off = 32; off >= 1; off >>= 1) sq += __shfl_xor(sq, off);
    float inv = rsqrtf(sq * (1.f / 128.f) + 1e-12f);
    float2 gv = reinterpret_cast<const float2*>(g)[lane];
    float2 bv = reinterpret_cast<const float2*>(b)[lane];
    float2 o;
    o.x = dx * inv * gv.x + bv.x;
    o.y = dy * inv * gv.y + bv.y;
    reinterpret_cast<float2*>(Out)[(size_t)r * 64 + lane] = o;
}

// ---------------------------------------------------------------------------
extern "C" void kernel_launch(void* const* d_in, const int* in_sizes, int n_in,
                              void* d_out, int out_size, void* d_ws, size_t ws_size,
                              hipStream_t stream)
{
    const float* x    = (const float*)d_in[0];
    const int*   edge = (const int*)d_in[1];     // int32 (harness converts int64)
    const float* W    = (const float*)d_in[2];
    const float* att  = (const float*)d_in[3];
    const float* bias = (const float*)d_in[4];
    const float* outW = (const float*)d_in[5];
    const float* outb = (const float*)d_in[6];
    const float* lng  = (const float*)d_in[7];
    const float* lnb  = (const float*)d_in[8];

    const int N  = in_sizes[0] / D;
    const int E  = in_sizes[1] / 2;
    const int NT = out_size / D;

    const int* srcp = edge;
    const int* dstp = edge + E;

    auto align256 = [](size_t v) { return (v + 255) & ~(size_t)255; };
    auto cdiv = [](int a, int b) { return (a + b - 1) / b; };

    const int NB = cdiv(N, 1024);    // scan blocks

    size_t ybytes = (size_t)NT * D * 4;
    size_t hb     = (size_t)N * D * 2;
    size_t hbytes = align256(hb > ybytes ? hb : ybytes);

    char* wp = (char*)d_ws;
    size_t off = 0;
    void* hbuf   = (void*)(wp + off); off += hbytes;
    unsigned short* wbf = (unsigned short*)(wp + off); off += align256((size_t)3 * D * D * 2);
    int*  rowptr = (int*)(wp + off);  off += align256((size_t)(N + 1) * 4);
    int*  cnt    = (int*)(wp + off);  off += align256((size_t)N * 4);
    int*  slist  = (int*)(wp + off);  off += align256((size_t)E * 4);
    int*  bsum   = (int*)(wp + off);
    unsigned int* xb = (unsigned int*)d_out;   // bf16 activations in d_out
    float* ybuf = (float*)hbuf;                // head GEMM out reuses h buffer
    (void)n_in; (void)ws_size;

    // ---- weight transpose+cast (once) ----
    transpose_w<<<3, 256, 0, stream>>>(W, outW, wbf);

    // ---- CSR build ----
    zero_ints<<<cdiv(N, 256), 256, 0, stream>>>(cnt, N);
    count_edges<<<cdiv(E, 256), 256, 0, stream>>>(dstp, cnt, E);
    scan_blocks<<<NB, 256, 0, stream>>>(cnt, rowptr, bsum, N);
    scan_bsums<<<1, 64, 0, stream>>>(bsum, NB);
    scan_add<<<NB, 256, 0, stream>>>(rowptr, bsum, N);
    zero_ints<<<cdiv(N, 256), 256, 0, stream>>>(cnt, N);
    scatter_edges<<<cdiv(E, 256), 256, 0, stream>>>(dstp, srcp, rowptr, cnt, slist, E);

    // ---- layer 0: h = x @ W0 (f32 in, bf16 out) ----
    gemm_mfma<0,1,0><<<cdiv(N, 64), 256, 0, stream>>>(x, wbf, nullptr, hbuf, N);
    aggregate<<<cdiv(N, 4), 256, 0, stream>>>((unsigned int*)hbuf, rowptr, slist,
                                              att, bias, xb, N);
    // ---- layer 1: h = gelu(x) @ W1 (bf16 in, bf16 out) ----
    gemm_mfma<1,1,1><<<cdiv(N, 64), 256, 0, stream>>>(xb, wbf + D * D, nullptr, hbuf, N);
    aggregate<<<cdiv(N, 4), 256, 0, stream>>>((unsigned int*)hbuf, rowptr, slist,
                                              att + H * C, bias + D, xb, N);
    // ---- head: y = x @ outW + outb (bf16 in, f32 out), then LN ----
    gemm_mfma<1,0,0><<<cdiv(NT, 64), 256, 0, stream>>>(xb, wbf + 2 * D * D, outb, ybuf, NT);
    ln_kernel<<<cdiv(NT, 4), 256, 0, stream>>>(ybuf, lng, lnb, (float*)d_out, NT);
}

// Round 10
// 261.393 us; speedup vs baseline: 2.6388x; 1.0011x over previous
//
#include <hip/hip_runtime.h>
#include <math.h>

// ---------------------------------------------------------------------------
// GATv2 encoder. r9: scatter_edges was #1 (51us, 56MB write amplification
// from random 4B scatter). Replaced with fused count+linked-list build
// (coalesced 8B node writes) + chain-walk compaction (sequential writes).
// Aggregate v4: no max-tracking (logits bounded; softmax shift-invariant),
// log2e folded into att -> raw v_exp_f32 per edge.
// ---------------------------------------------------------------------------

#define D 128
#define H 8
#define C 16

typedef __attribute__((ext_vector_type(8))) short bf16x8v;
typedef __attribute__((ext_vector_type(4))) float f32x4v;

static __device__ __forceinline__ float bf2f(unsigned int u16) {
    union { unsigned int i; float f; } x; x.i = u16 << 16; return x.f;
}
static __device__ __forceinline__ unsigned short f2bf(float f) {
    union { float f; unsigned int i; } x; x.f = f;
    unsigned int r = x.i + 0x7fffu + ((x.i >> 16) & 1u);   // RNE
    return (unsigned short)(r >> 16);
}
static __device__ __forceinline__ float gelu_f(float v) {
    return 0.5f * v * (1.0f + erff(v * 0.70710678118654752f));
}
static __device__ __forceinline__ float exp2_hw(float x) {   // v_exp_f32 = 2^x
    float r;
    asm("v_exp_f32 %0, %1" : "=v"(r) : "v"(x));
    return r;
}
// DPP-powered cross-lane add: v += lane[ctrl-permuted]
#define DPP_ADD(v, ctrl) \
    (v) += __builtin_bit_cast(float, __builtin_amdgcn_update_dpp( \
        0, __builtin_bit_cast(int, (v)), (ctrl), 0xf, 0xf, true))

// ---------------- W transpose+cast: Wt[n][k] bf16 from W[k][n] f32 ----------
__global__ __launch_bounds__(256) void transpose_w(
    const float* __restrict__ W, const float* __restrict__ outW,
    unsigned short* __restrict__ wbf)
{
    int b = blockIdx.x, t = threadIdx.x;
    const float* src = (b < 2) ? (W + (size_t)b * D * D) : outW;
    unsigned short* dst = wbf + (size_t)b * D * D;
#pragma unroll
    for (int i = 0; i < 64; ++i) {
        int idx = i * 256 + t;          // 0..16383
        int k = idx >> 7, n = idx & 127;
        dst[n * D + k] = f2bf(src[idx]);
    }
}

// ----------------------------- MFMA GEMM -----------------------------------
// Out[nrows x 128] = act(X[nrows x 128]) @ W (+bias).  Wt bf16 [n][k].
// A-frags direct global->VGPR (no reuse); W in XOR-swizzled LDS (2-way=free).
template<int IN_BF, int OUT_BF, int GELU>
__global__ __launch_bounds__(256) void gemm_mfma(
    const void* __restrict__ Xv, const unsigned short* __restrict__ Wt,
    const float* __restrict__ bias, void* __restrict__ Outv, int nrows)
{
    __shared__ short Wlds[128 * 128];   // 32 KB

    const int t  = threadIdx.x;
    const int m0 = blockIdx.x * 64;

#pragma unroll
    for (int w = 0; w < 8; ++w) {
        int cell = w * 256 + t;
        int col = cell >> 4, kg = cell & 15;
        uint4 q = reinterpret_cast<const uint4*>(Wt)[col * 16 + kg];
        *reinterpret_cast<uint4*>(&Wlds[(col * 16 + (kg ^ (col & 7))) * 8]) = q;
    }

    const int l  = t & 63;
    const int wv = t >> 6;
    const int g  = l >> 4;
    const int r  = l & 15;
    const int row = m0 + wv * 16 + r;
    const bool rv = row < nrows;

    bf16x8v afrag[4];
#pragma unroll
    for (int kk = 0; kk < 4; ++kk) {
        int kg = kk * 4 + g;
        float v[8];
        if (IN_BF) {
            uint4 q = make_uint4(0, 0, 0, 0);
            if (rv) q = reinterpret_cast<const uint4*>(Xv)[(size_t)row * 16 + kg];
            if (GELU) {
                unsigned int qq[4] = {q.x, q.y, q.z, q.w};
#pragma unroll
                for (int j = 0; j < 4; ++j) {
                    v[2 * j]     = gelu_f(bf2f(qq[j] & 0xffffu));
                    v[2 * j + 1] = gelu_f(bf2f(qq[j] >> 16));
                }
                short pk[8];
#pragma unroll
                for (int j = 0; j < 8; ++j) pk[j] = (short)f2bf(v[j]);
                afrag[kk] = *reinterpret_cast<bf16x8v*>(pk);
            } else {
                afrag[kk] = __builtin_bit_cast(bf16x8v, q);
            }
        } else {
            float4 a = make_float4(0.f, 0.f, 0.f, 0.f), b = a;
            if (rv) {
                a = reinterpret_cast<const float4*>(Xv)[(size_t)row * 32 + kg * 2];
                b = reinterpret_cast<const float4*>(Xv)[(size_t)row * 32 + kg * 2 + 1];
            }
            v[0] = a.x; v[1] = a.y; v[2] = a.z; v[3] = a.w;
            v[4] = b.x; v[5] = b.y; v[6] = b.z; v[7] = b.w;
            if (GELU) {
#pragma unroll
                for (int j = 0; j < 8; ++j) v[j] = gelu_f(v[j]);
            }
            short pk[8];
#pragma unroll
            for (int j = 0; j < 8; ++j) pk[j] = (short)f2bf(v[j]);
            afrag[kk] = *reinterpret_cast<bf16x8v*>(pk);
        }
    }
    __syncthreads();

    f32x4v acc[8];
#pragma unroll
    for (int ct = 0; ct < 8; ++ct) acc[ct] = (f32x4v){0.f, 0.f, 0.f, 0.f};

#pragma unroll
    for (int kk = 0; kk < 4; ++kk) {
        int kg = kk * 4 + g;
#pragma unroll
        for (int ct = 0; ct < 8; ++ct) {
            int col = ct * 16 + r;
            bf16x8v b = *reinterpret_cast<const bf16x8v*>(
                &Wlds[(col * 16 + (kg ^ (col & 7))) * 8]);
            acc[ct] = __builtin_amdgcn_mfma_f32_16x16x32_bf16(afrag[kk], b, acc[ct], 0, 0, 0);
        }
    }

#pragma unroll
    for (int ct = 0; ct < 8; ++ct) {
        int col = ct * 16 + r;
        float bj = bias ? bias[col] : 0.f;
#pragma unroll
        for (int i = 0; i < 4; ++i) {
            int rr = m0 + wv * 16 + g * 4 + i;
            if (rr < nrows) {
                float val = acc[ct][i] + bj;
                if (OUT_BF)
                    reinterpret_cast<unsigned short*>(Outv)[(size_t)rr * 128 + col] = f2bf(val);
                else
                    reinterpret_cast<float*>(Outv)[(size_t)rr * 128 + col] = val;
            }
        }
    }
}

// ------------------------- CSR build (linked list) -------------------------
__global__ void init_csr(int* __restrict__ cnt, int* __restrict__ head, int n)
{
    int stride = gridDim.x * blockDim.x;
    for (int i = blockIdx.x * blockDim.x + threadIdx.x; i < n; i += stride) {
        cnt[i] = 0;
        head[i] = -1;
    }
}

// fused: degree count + linked-list insert; node[e] = {next, src[e]} coalesced
__global__ void count_and_link(const int* __restrict__ dst,
                               const int* __restrict__ src,
                               int* __restrict__ cnt, int* __restrict__ head,
                               int2* __restrict__ node, int E)
{
    int t = blockIdx.x * blockDim.x + threadIdx.x;
    if (t < E) {
        int d = dst[t];
        atomicAdd(&cnt[d], 1);
        int old = atomicExch(&head[d], t);
        node[t] = make_int2(old, src[t]);
    }
}

__global__ __launch_bounds__(256) void scan_blocks(
    const int* __restrict__ cnt, int* __restrict__ rowptr,
    int* __restrict__ bsum, int n)
{
    __shared__ int sh[256];
    const int b = blockIdx.x, t = threadIdx.x;
    const int base = b * 1024 + t * 4;
    int v0 = 0, v1 = 0, v2 = 0, v3 = 0;
    if (base + 3 < n) {
        int4 q = *reinterpret_cast<const int4*>(cnt + base);
        v0 = q.x; v1 = q.y; v2 = q.z; v3 = q.w;
    } else {
        if (base     < n) v0 = cnt[base];
        if (base + 1 < n) v1 = cnt[base + 1];
        if (base + 2 < n) v2 = cnt[base + 2];
        if (base + 3 < n) v3 = cnt[base + 3];
    }
    int s = v0 + v1 + v2 + v3;
    sh[t] = s;
    __syncthreads();
#pragma unroll
    for (int off = 1; off < 256; off <<= 1) {
        int x = (t >= off) ? sh[t - off] : 0;
        __syncthreads();
        sh[t] += x;
        __syncthreads();
    }
    int excl = sh[t] - s;
    int p0 = excl + v0, p1 = p0 + v1, p2 = p1 + v2, p3 = p2 + v3;
    if (base     < n) rowptr[base + 1] = p0;
    if (base + 1 < n) rowptr[base + 2] = p1;
    if (base + 2 < n) rowptr[base + 3] = p2;
    if (base + 3 < n) rowptr[base + 4] = p3;
    if (t == 255) bsum[b] = sh[255];
}

__global__ void scan_bsums(int* __restrict__ bsum, int nb)
{
    __shared__ int carry;
    int t = threadIdx.x & 63;
    if (threadIdx.x == 0) carry = 0;
    __syncthreads();
    for (int base = 0; base < nb; base += 64) {
        int v = (base + t < nb) ? bsum[base + t] : 0;
#pragma unroll
        for (int off = 1; off < 64; off <<= 1) {
            int y = __shfl_up(v, off);
            if (t >= off) v += y;
        }
        int c = carry;
        __syncthreads();
        if (base + t < nb) bsum[base + t] = v + c;
        if (t == 63) carry = c + v;
        __syncthreads();
    }
}

__global__ __launch_bounds__(256) void scan_add(
    int* __restrict__ rowptr, const int* __restrict__ bsum, int n)
{
    int b = blockIdx.x, t = threadIdx.x;
    if (b == 0 && t == 0) rowptr[0] = 0;
    int ofs = (b == 0) ? 0 : bsum[b - 1];
    if (ofs == 0) return;
    int idx = b * 1024 + t * 4 + 1;
#pragma unroll
    for (int k = 0; k < 4; ++k)
        if (idx + k <= n) rowptr[idx + k] += ofs;
}

// walk chains: thread per dst; sequential slist writes (no amplification)
__global__ void walk_list(const int* __restrict__ head,
                          const int2* __restrict__ node,
                          const int* __restrict__ rowptr,
                          int* __restrict__ slist, int n)
{
    int d = blockIdx.x * blockDim.x + threadIdx.x;
    if (d < n) {
        int p = rowptr[d];
        int e = head[d];
        while (e >= 0) {
            int2 nd = node[e];
            slist[p++] = nd.y;
            e = nd.x;
        }
    }
}

// ----------- fused logits + softmax + aggregate (no max-tracking) ----------
// wave per dst node; lane = channels (2*lane,2*lane+1); head = lane>>3.
// logits bounded (|p|<<88) -> no max subtraction needed (shift-invariant).
// att pre-scaled by log2e -> e = v_exp_f32(p) directly.
#define EDGE_PRE(k) \
    unsigned int u##k = Hm[((unsigned)s##k << 6) | lane]; \
    float h##k##x = bf2f(u##k & 0xffffu), h##k##y = bf2f(u##k >> 16); \
    float a##k = h##k##x + hdx; a##k = fmaxf(a##k, 0.2f * a##k); \
    float b##k = h##k##y + hdy; b##k = fmaxf(b##k, 0.2f * b##k); \
    float p##k = a##k * aw.x + b##k * aw.y; \
    DPP_ADD(p##k, 0xB1); DPP_ADD(p##k, 0x4E); DPP_ADD(p##k, 0x141); \
    float e##k = exp2_hw(p##k);

__global__ __launch_bounds__(256) void aggregate(
    const unsigned int* __restrict__ Hm,
    const int* __restrict__ rowptr, const int* __restrict__ slist,
    const float* __restrict__ att, const float* __restrict__ bias,
    unsigned int* __restrict__ Outv, int n)
{
    int wid  = threadIdx.x >> 6;
    int lane = threadIdx.x & 63;
    int d = blockIdx.x * 4 + wid;
    if (d >= n) return;

    int beg = rowptr[d];
    int end = rowptr[d + 1];

    unsigned int ud = Hm[((unsigned)d << 6) | lane];
    float hdx = bf2f(ud & 0xffffu), hdy = bf2f(ud >> 16);
    float2 aw = reinterpret_cast<const float2*>(att)[lane];
    aw.x *= 1.44269504088896f;    // fold log2(e): exp(p) = 2^(p*log2e)
    aw.y *= 1.44269504088896f;

    float ssum = 0.f, accx = 0.f, accy = 0.f;

    int i = beg;
    for (; i + 3 < end; i += 4) {
        int s0 = slist[i], s1 = slist[i + 1], s2 = slist[i + 2], s3 = slist[i + 3];
        EDGE_PRE(0) EDGE_PRE(1) EDGE_PRE(2) EDGE_PRE(3)
        ssum += (e0 + e1) + (e2 + e3);
        accx = fmaf(e0, h0x, fmaf(e1, h1x, fmaf(e2, h2x, fmaf(e3, h3x, accx))));
        accy = fmaf(e0, h0y, fmaf(e1, h1y, fmaf(e2, h2y, fmaf(e3, h3y, accy))));
    }
    for (; i < end; ++i) {
        int s0 = slist[i];
        EDGE_PRE(0)
        ssum += e0;
        accx = fmaf(e0, h0x, accx);
        accy = fmaf(e0, h0y, accy);
    }

    float inv = 1.f / (ssum + 1e-16f);
    float2 bv = reinterpret_cast<const float2*>(bias)[lane];
    float ox = accx * inv + bv.x;
    float oy = accy * inv + bv.y;
    Outv[((unsigned)d << 6) | lane] =
        (unsigned int)f2bf(ox) | ((unsigned int)f2bf(oy) << 16);
}

// ------------------------------ LayerNorm ----------------------------------
__global__ __launch_bounds__(256) void ln_kernel(
    const float* __restrict__ Y, const float* __restrict__ g,
    const float* __restrict__ b, float* __restrict__ Out, int n)
{
    int wid  = threadIdx.x >> 6;
    int lane = threadIdx.x & 63;
    int r = blockIdx.x * 4 + wid;
    if (r >= n) return;

    float2 v = reinterpret_cast<const float2*>(Y)[(size_t)r * 64 + lane];
    float sum = v.x + v.y;
#pragma unroll
    for (int off = 32; off >= 1; off >>= 1) sum += __shfl_xor(sum, off);
    float mu = sum * (1.f / 128.f);
    float dx = v.x - mu, dy = v.y - mu;
    float sq = dx * dx + dy * dy;
#pragma unroll
    for (int off = 32; off >= 1; off >>= 1) sq += __shfl_xor(sq, off);
    float inv = rsqrtf(sq * (1.f / 128.f) + 1e-12f);
    float2 gv = reinterpret_cast<const float2*>(g)[lane];
    float2 bv = reinterpret_cast<const float2*>(b)[lane];
    float2 o;
    o.x = dx * inv * gv.x + bv.x;
    o.y = dy * inv * gv.y + bv.y;
    reinterpret_cast<float2*>(Out)[(size_t)r * 64 + lane] = o;
}

// ---------------------------------------------------------------------------
extern "C" void kernel_launch(void* const* d_in, const int* in_sizes, int n_in,
                              void* d_out, int out_size, void* d_ws, size_t ws_size,
                              hipStream_t stream)
{
    const float* x    = (const float*)d_in[0];
    const int*   edge = (const int*)d_in[1];     // int32 (harness converts int64)
    const float* W    = (const float*)d_in[2];
    const float* att  = (const float*)d_in[3];
    const float* bias = (const float*)d_in[4];
    const float* outW = (const float*)d_in[5];
    const float* outb = (const float*)d_in[6];
    const float* lng  = (const float*)d_in[7];
    const float* lnb  = (const float*)d_in[8];

    const int N  = in_sizes[0] / D;
    const int E  = in_sizes[1] / 2;
    const int NT = out_size / D;

    const int* srcp = edge;
    const int* dstp = edge + E;

    auto align256 = [](size_t v) { return (v + 255) & ~(size_t)255; };
    auto cdiv = [](int a, int b) { return (a + b - 1) / b; };

    const int NB = cdiv(N, 1024);    // scan blocks

    size_t ybytes = (size_t)NT * D * 4;
    size_t hb     = (size_t)N * D * 2;
    size_t hbytes = align256(hb > ybytes ? hb : ybytes);

    char* wp = (char*)d_ws;
    size_t off = 0;
    void* hbuf   = (void*)(wp + off); off += hbytes;
    unsigned short* wbf = (unsigned short*)(wp + off); off += align256((size_t)3 * D * D * 2);
    int*  rowptr = (int*)(wp + off);  off += align256((size_t)(N + 1) * 4);
    int*  cnt    = (int*)(wp + off);  off += align256((size_t)N * 4);   // also head
    int*  slist  = (int*)(wp + off);  off += align256((size_t)E * 4);
    int2* node   = (int2*)(wp + off); off += align256((size_t)E * 8);
    int*  head   = (int*)(wp + off);  off += align256((size_t)N * 4);
    int*  bsum   = (int*)(wp + off);
    unsigned int* xb = (unsigned int*)d_out;   // bf16 activations in d_out
    float* ybuf = (float*)hbuf;                // head GEMM out reuses h buffer
    (void)n_in; (void)ws_size;

    // ---- weight transpose+cast (once) ----
    transpose_w<<<3, 256, 0, stream>>>(W, outW, wbf);

    // ---- CSR build: count+link fused, scan, walk ----
    init_csr<<<cdiv(N, 256), 256, 0, stream>>>(cnt, head, N);
    count_and_link<<<cdiv(E, 256), 256, 0, stream>>>(dstp, srcp, cnt, head, node, E);
    scan_blocks<<<NB, 256, 0, stream>>>(cnt, rowptr, bsum, N);
    scan_bsums<<<1, 64, 0, stream>>>(bsum, NB);
    scan_add<<<NB, 256, 0, stream>>>(rowptr, bsum, N);
    walk_list<<<cdiv(N, 256), 256, 0, stream>>>(head, node, rowptr, slist, N);

    // ---- layer 0: h = x @ W0 (f32 in, bf16 out) ----
    gemm_mfma<0,1,0><<<cdiv(N, 64), 256, 0, stream>>>(x, wbf, nullptr, hbuf, N);
    aggregate<<<cdiv(N, 4), 256, 0, stream>>>((unsigned int*)hbuf, rowptr, slist,
                                              att, bias, xb, N);
    // ---- layer 1: h = gelu(x) @ W1 (bf16 in, bf16 out) ----
    gemm_mfma<1,1,1><<<cdiv(N, 64), 256, 0, stream>>>(xb, wbf + D * D, nullptr, hbuf, N);
    aggregate<<<cdiv(N, 4), 256, 0, stream>>>((unsigned int*)hbuf, rowptr, slist,
                                              att + H * C, bias + D, xb, N);
    // ---- head: y = x @ outW + outb (bf16 in, f32 out), then LN ----
    gemm_mfma<1,0,0><<<cdiv(NT, 64), 256, 0, stream>>>(xb, wbf + 2 * D * D, outb, ybuf, NT);
    ln_kernel<<<cdiv(NT, 4), 256, 0, stream>>>(ybuf, lng, lnb, (float*)d_out, NT);
}

// Round 11
// 192.497 us; speedup vs baseline: 3.5832x; 1.3579x over previous
//
#include <hip/hip_runtime.h>
#include <math.h>

// ---------------------------------------------------------------------------
// GATv2 encoder. r10 lesson: each random global atomic ~ 32B HBM write-through
// (1.6M atomics = 50MB WRITE_SIZE). New CSR build: bucket-by-(dst>>8) with
// LDS histograms + precomputed per-block offsets -> zero global atomics in
// the per-edge path; per-bucket LDS count/rank; slist writes L2-resident.
// Aggregate v4 (no max-tracking, hw exp2) and MFMA GEMM unchanged.
// ---------------------------------------------------------------------------

#define D 128
#define H 8
#define C 16
#define NBIN 256

typedef __attribute__((ext_vector_type(8))) short bf16x8v;
typedef __attribute__((ext_vector_type(4))) float f32x4v;

static __device__ __forceinline__ float bf2f(unsigned int u16) {
    union { unsigned int i; float f; } x; x.i = u16 << 16; return x.f;
}
static __device__ __forceinline__ unsigned short f2bf(float f) {
    union { float f; unsigned int i; } x; x.f = f;
    unsigned int r = x.i + 0x7fffu + ((x.i >> 16) & 1u);   // RNE
    return (unsigned short)(r >> 16);
}
static __device__ __forceinline__ float gelu_f(float v) {
    return 0.5f * v * (1.0f + erff(v * 0.70710678118654752f));
}
static __device__ __forceinline__ float exp2_hw(float x) {   // v_exp_f32 = 2^x
    float r;
    asm("v_exp_f32 %0, %1" : "=v"(r) : "v"(x));
    return r;
}
#define DPP_ADD(v, ctrl) \
    (v) += __builtin_bit_cast(float, __builtin_amdgcn_update_dpp( \
        0, __builtin_bit_cast(int, (v)), (ctrl), 0xf, 0xf, true))

// ---------------- W transpose+cast (parallel, LDS-tiled) --------------------
// grid 24: matrix = blk>>3 (W0,W1,outW), 16-col slab = blk&7
__global__ __launch_bounds__(256) void transpose_w2(
    const float* __restrict__ W, const float* __restrict__ outW,
    unsigned short* __restrict__ wbf)
{
    __shared__ unsigned short tile[128][17];
    int blk = blockIdx.x, t = threadIdx.x;
    int mat = blk >> 3, s = blk & 7;
    const float* src = (mat < 2) ? (W + (size_t)mat * D * D) : outW;
    unsigned short* dst = wbf + (size_t)mat * D * D;
    int n0 = s * 16;
#pragma unroll
    for (int it = 0; it < 8; ++it) {
        int idx = it * 256 + t;          // 0..2047
        int k = idx >> 4, n = idx & 15;  // load coalesced over n,k
        tile[k][n] = f2bf(src[k * D + n0 + n]);
    }
    __syncthreads();
#pragma unroll
    for (int it = 0; it < 8; ++it) {
        int idx = it * 256 + t;
        int n = idx >> 7, k = idx & 127; // store coalesced over k
        dst[(size_t)(n0 + n) * D + k] = tile[k][n];
    }
}

// ----------------------------- MFMA GEMM -----------------------------------
template<int IN_BF, int OUT_BF, int GELU>
__global__ __launch_bounds__(256) void gemm_mfma(
    const void* __restrict__ Xv, const unsigned short* __restrict__ Wt,
    const float* __restrict__ bias, void* __restrict__ Outv, int nrows)
{
    __shared__ short Wlds[128 * 128];   // 32 KB

    const int t  = threadIdx.x;
    const int m0 = blockIdx.x * 64;

#pragma unroll
    for (int w = 0; w < 8; ++w) {
        int cell = w * 256 + t;
        int col = cell >> 4, kg = cell & 15;
        uint4 q = reinterpret_cast<const uint4*>(Wt)[col * 16 + kg];
        *reinterpret_cast<uint4*>(&Wlds[(col * 16 + (kg ^ (col & 7))) * 8]) = q;
    }

    const int l  = t & 63;
    const int wv = t >> 6;
    const int g  = l >> 4;
    const int r  = l & 15;
    const int row = m0 + wv * 16 + r;
    const bool rv = row < nrows;

    bf16x8v afrag[4];
#pragma unroll
    for (int kk = 0; kk < 4; ++kk) {
        int kg = kk * 4 + g;
        float v[8];
        if (IN_BF) {
            uint4 q = make_uint4(0, 0, 0, 0);
            if (rv) q = reinterpret_cast<const uint4*>(Xv)[(size_t)row * 16 + kg];
            if (GELU) {
                unsigned int qq[4] = {q.x, q.y, q.z, q.w};
#pragma unroll
                for (int j = 0; j < 4; ++j) {
                    v[2 * j]     = gelu_f(bf2f(qq[j] & 0xffffu));
                    v[2 * j + 1] = gelu_f(bf2f(qq[j] >> 16));
                }
                short pk[8];
#pragma unroll
                for (int j = 0; j < 8; ++j) pk[j] = (short)f2bf(v[j]);
                afrag[kk] = *reinterpret_cast<bf16x8v*>(pk);
            } else {
                afrag[kk] = __builtin_bit_cast(bf16x8v, q);
            }
        } else {
            float4 a = make_float4(0.f, 0.f, 0.f, 0.f), b = a;
            if (rv) {
                a = reinterpret_cast<const float4*>(Xv)[(size_t)row * 32 + kg * 2];
                b = reinterpret_cast<const float4*>(Xv)[(size_t)row * 32 + kg * 2 + 1];
            }
            v[0] = a.x; v[1] = a.y; v[2] = a.z; v[3] = a.w;
            v[4] = b.x; v[5] = b.y; v[6] = b.z; v[7] = b.w;
            if (GELU) {
#pragma unroll
                for (int j = 0; j < 8; ++j) v[j] = gelu_f(v[j]);
            }
            short pk[8];
#pragma unroll
            for (int j = 0; j < 8; ++j) pk[j] = (short)f2bf(v[j]);
            afrag[kk] = *reinterpret_cast<bf16x8v*>(pk);
        }
    }
    __syncthreads();

    f32x4v acc[8];
#pragma unroll
    for (int ct = 0; ct < 8; ++ct) acc[ct] = (f32x4v){0.f, 0.f, 0.f, 0.f};

#pragma unroll
    for (int kk = 0; kk < 4; ++kk) {
        int kg = kk * 4 + g;
#pragma unroll
        for (int ct = 0; ct < 8; ++ct) {
            int col = ct * 16 + r;
            bf16x8v b = *reinterpret_cast<const bf16x8v*>(
                &Wlds[(col * 16 + (kg ^ (col & 7))) * 8]);
            acc[ct] = __builtin_amdgcn_mfma_f32_16x16x32_bf16(afrag[kk], b, acc[ct], 0, 0, 0);
        }
    }

#pragma unroll
    for (int ct = 0; ct < 8; ++ct) {
        int col = ct * 16 + r;
        float bj = bias ? bias[col] : 0.f;
#pragma unroll
        for (int i = 0; i < 4; ++i) {
            int rr = m0 + wv * 16 + g * 4 + i;
            if (rr < nrows) {
                float val = acc[ct][i] + bj;
                if (OUT_BF)
                    reinterpret_cast<unsigned short*>(Outv)[(size_t)rr * 128 + col] = f2bf(val);
                else
                    reinterpret_cast<float*>(Outv)[(size_t)rr * 128 + col] = val;
            }
        }
    }
}

// ------------------- CSR build: LDS-bucketed, no global atomics ------------
// buckets = dst>>8 (256 dsts each). bh layout: [bin][blk] (bin-major).

__global__ __launch_bounds__(256) void hist_pass(
    const int* __restrict__ dst, int* __restrict__ bh, int E, int chunk, int nblk)
{
    __shared__ int h[NBIN];
    int t = threadIdx.x, b = blockIdx.x;
    h[t] = 0;
    __syncthreads();
    int lo = b * chunk, hi = min(E, lo + chunk);
    for (int i = lo + t; i < hi; i += 256) atomicAdd(&h[dst[i] >> 8], 1);
    __syncthreads();
    bh[t * nblk + b] = h[t];
}

// per-bin exclusive scan over blocks (in place); tot[bin] = bin total
__global__ __launch_bounds__(256) void bin_scan(
    int* __restrict__ bh, int* __restrict__ tot, int nblk)
{
    __shared__ int sh[256];
    int bin = blockIdx.x, t = threadIdx.x;
    int v = (t < nblk) ? bh[bin * nblk + t] : 0;
    sh[t] = v;
    __syncthreads();
#pragma unroll
    for (int off = 1; off < 256; off <<= 1) {
        int x = (t >= off) ? sh[t - off] : 0;
        __syncthreads();
        sh[t] += x;
        __syncthreads();
    }
    if (t < nblk) bh[bin * nblk + t] = sh[t] - v;   // exclusive
    if (t == 255) tot[bin] = sh[255];
}

// exclusive scan of 256 bin totals -> bases[0..256]
__global__ __launch_bounds__(256) void base_scan(
    const int* __restrict__ tot, int* __restrict__ bases)
{
    __shared__ int sh[256];
    int t = threadIdx.x;
    int v = tot[t];
    sh[t] = v;
    __syncthreads();
#pragma unroll
    for (int off = 1; off < 256; off <<= 1) {
        int x = (t >= off) ? sh[t - off] : 0;
        __syncthreads();
        sh[t] += x;
        __syncthreads();
    }
    bases[t] = sh[t] - v;
    if (t == 255) bases[256] = sh[255];
}

// scatter edges into bucket-contiguous buffer; cursors start at exact
// precomputed offsets -> only LDS atomics.
__global__ __launch_bounds__(256) void scatter_bucket(
    const int* __restrict__ dst, const int* __restrict__ src,
    const int* __restrict__ bh, const int* __restrict__ bases,
    int2* __restrict__ bout, int E, int chunk, int nblk)
{
    __shared__ int cur[NBIN];
    int t = threadIdx.x, b = blockIdx.x;
    cur[t] = bases[t] + bh[t * nblk + b];
    __syncthreads();
    int lo = b * chunk, hi = min(E, lo + chunk);
    for (int i = lo + t; i < hi; i += 256) {
        int d = dst[i];
        int p = atomicAdd(&cur[d >> 8], 1);
        bout[p] = make_int2(src[i], d);
    }
}

// per-bucket degree count (LDS), coalesced cnt write
__global__ __launch_bounds__(256) void count_bucket(
    const int2* __restrict__ bout, const int* __restrict__ bases,
    int* __restrict__ cnt, int N)
{
    __shared__ int c[NBIN];
    int t = threadIdx.x, b = blockIdx.x;
    c[t] = 0;
    __syncthreads();
    int lo = bases[b], hi = bases[b + 1];
    for (int i = lo + t; i < hi; i += 256) atomicAdd(&c[bout[i].y & 255], 1);
    __syncthreads();
    int d = b * 256 + t;
    if (d < N) cnt[d] = c[t];
}

// per-bucket rank + fill slist (writes land in ~51KB L2-resident window)
__global__ __launch_bounds__(256) void fill_bucket(
    const int2* __restrict__ bout, const int* __restrict__ bases,
    const int* __restrict__ rowptr, int* __restrict__ slist, int N)
{
    __shared__ int cur[NBIN];
    int t = threadIdx.x, b = blockIdx.x;
    int d0 = b * 256 + t;
    cur[t] = (d0 < N) ? rowptr[d0] : 0;
    __syncthreads();
    int lo = bases[b], hi = bases[b + 1];
    for (int i = lo + t; i < hi; i += 256) {
        int2 e = bout[i];
        int p = atomicAdd(&cur[e.y & 255], 1);
        slist[p] = e.x;
    }
}

// ---- rowptr scan (multi-block) ----
__global__ __launch_bounds__(256) void scan_blocks(
    const int* __restrict__ cnt, int* __restrict__ rowptr,
    int* __restrict__ bsum, int n)
{
    __shared__ int sh[256];
    const int b = blockIdx.x, t = threadIdx.x;
    const int base = b * 1024 + t * 4;
    int v0 = 0, v1 = 0, v2 = 0, v3 = 0;
    if (base + 3 < n) {
        int4 q = *reinterpret_cast<const int4*>(cnt + base);
        v0 = q.x; v1 = q.y; v2 = q.z; v3 = q.w;
    } else {
        if (base     < n) v0 = cnt[base];
        if (base + 1 < n) v1 = cnt[base + 1];
        if (base + 2 < n) v2 = cnt[base + 2];
        if (base + 3 < n) v3 = cnt[base + 3];
    }
    int s = v0 + v1 + v2 + v3;
    sh[t] = s;
    __syncthreads();
#pragma unroll
    for (int off = 1; off < 256; off <<= 1) {
        int x = (t >= off) ? sh[t - off] : 0;
        __syncthreads();
        sh[t] += x;
        __syncthreads();
    }
    int excl = sh[t] - s;
    int p0 = excl + v0, p1 = p0 + v1, p2 = p1 + v2, p3 = p2 + v3;
    if (base     < n) rowptr[base + 1] = p0;
    if (base + 1 < n) rowptr[base + 2] = p1;
    if (base + 2 < n) rowptr[base + 3] = p2;
    if (base + 3 < n) rowptr[base + 4] = p3;
    if (t == 255) bsum[b] = sh[255];
}

__global__ void scan_bsums(int* __restrict__ bsum, int nb)
{
    __shared__ int carry;
    int t = threadIdx.x & 63;
    if (threadIdx.x == 0) carry = 0;
    __syncthreads();
    for (int base = 0; base < nb; base += 64) {
        int v = (base + t < nb) ? bsum[base + t] : 0;
#pragma unroll
        for (int off = 1; off < 64; off <<= 1) {
            int y = __shfl_up(v, off);
            if (t >= off) v += y;
        }
        int c = carry;
        __syncthreads();
        if (base + t < nb) bsum[base + t] = v + c;
        if (t == 63) carry = c + v;
        __syncthreads();
    }
}

__global__ __launch_bounds__(256) void scan_add(
    int* __restrict__ rowptr, const int* __restrict__ bsum, int n)
{
    int b = blockIdx.x, t = threadIdx.x;
    if (b == 0 && t == 0) rowptr[0] = 0;
    int ofs = (b == 0) ? 0 : bsum[b - 1];
    if (ofs == 0) return;
    int idx = b * 1024 + t * 4 + 1;
#pragma unroll
    for (int k = 0; k < 4; ++k)
        if (idx + k <= n) rowptr[idx + k] += ofs;
}

// ----------- fused logits + softmax + aggregate (no max-tracking) ----------
#define EDGE_PRE(k) \
    unsigned int u##k = Hm[((unsigned)s##k << 6) | lane]; \
    float h##k##x = bf2f(u##k & 0xffffu), h##k##y = bf2f(u##k >> 16); \
    float a##k = h##k##x + hdx; a##k = fmaxf(a##k, 0.2f * a##k); \
    float b##k = h##k##y + hdy; b##k = fmaxf(b##k, 0.2f * b##k); \
    float p##k = a##k * aw.x + b##k * aw.y; \
    DPP_ADD(p##k, 0xB1); DPP_ADD(p##k, 0x4E); DPP_ADD(p##k, 0x141); \
    float e##k = exp2_hw(p##k);

__global__ __launch_bounds__(256) void aggregate(
    const unsigned int* __restrict__ Hm,
    const int* __restrict__ rowptr, const int* __restrict__ slist,
    const float* __restrict__ att, const float* __restrict__ bias,
    unsigned int* __restrict__ Outv, int n)
{
    int wid  = threadIdx.x >> 6;
    int lane = threadIdx.x & 63;
    int d = blockIdx.x * 4 + wid;
    if (d >= n) return;

    int beg = rowptr[d];
    int end = rowptr[d + 1];

    unsigned int ud = Hm[((unsigned)d << 6) | lane];
    float hdx = bf2f(ud & 0xffffu), hdy = bf2f(ud >> 16);
    float2 aw = reinterpret_cast<const float2*>(att)[lane];
    aw.x *= 1.44269504088896f;    // fold log2(e): exp(p) = 2^(p*log2e)
    aw.y *= 1.44269504088896f;

    float ssum = 0.f, accx = 0.f, accy = 0.f;

    int i = beg;
    for (; i + 3 < end; i += 4) {
        int s0 = slist[i], s1 = slist[i + 1], s2 = slist[i + 2], s3 = slist[i + 3];
        EDGE_PRE(0) EDGE_PRE(1) EDGE_PRE(2) EDGE_PRE(3)
        ssum += (e0 + e1) + (e2 + e3);
        accx = fmaf(e0, h0x, fmaf(e1, h1x, fmaf(e2, h2x, fmaf(e3, h3x, accx))));
        accy = fmaf(e0, h0y, fmaf(e1, h1y, fmaf(e2, h2y, fmaf(e3, h3y, accy))));
    }
    for (; i < end; ++i) {
        int s0 = slist[i];
        EDGE_PRE(0)
        ssum += e0;
        accx = fmaf(e0, h0x, accx);
        accy = fmaf(e0, h0y, accy);
    }

    float inv = 1.f / (ssum + 1e-16f);
    float2 bv = reinterpret_cast<const float2*>(bias)[lane];
    float ox = accx * inv + bv.x;
    float oy = accy * inv + bv.y;
    Outv[((unsigned)d << 6) | lane] =
        (unsigned int)f2bf(ox) | ((unsigned int)f2bf(oy) << 16);
}

// ------------------------------ LayerNorm ----------------------------------
__global__ __launch_bounds__(256) void ln_kernel(
    const float* __restrict__ Y, const float* __restrict__ g,
    const float* __restrict__ b, float* __restrict__ Out, int n)
{
    int wid  = threadIdx.x >> 6;
    int lane = threadIdx.x & 63;
    int r = blockIdx.x * 4 + wid;
    if (r >= n) return;

    float2 v = reinterpret_cast<const float2*>(Y)[(size_t)r * 64 + lane];
    float sum = v.x + v.y;
#pragma unroll
    for (int off = 32; off >= 1; off >>= 1) sum += __shfl_xor(sum, off);
    float mu = sum * (1.f / 128.f);
    float dx = v.x - mu, dy = v.y - mu;
    float sq = dx * dx + dy * dy;
#pragma unroll
    for (int off = 32; off >= 1; off >>= 1) sq += __shfl_xor(sq, off);
    float inv = rsqrtf(sq * (1.f / 128.f) + 1e-12f);
    float2 gv = reinterpret_cast<const float2*>(g)[lane];
    float2 bv = reinterpret_cast<const float2*>(b)[lane];
    float2 o;
    o.x = dx * inv * gv.x + bv.x;
    o.y = dy * inv * gv.y + bv.y;
    reinterpret_cast<float2*>(Out)[(size_t)r * 64 + lane] = o;
}

// ---------------------------------------------------------------------------
extern "C" void kernel_launch(void* const* d_in, const int* in_sizes, int n_in,
                              void* d_out, int out_size, void* d_ws, size_t ws_size,
                              hipStream_t stream)
{
    const float* x    = (const float*)d_in[0];
    const int*   edge = (const int*)d_in[1];     // int32 (harness converts int64)
    const float* W    = (const float*)d_in[2];
    const float* att  = (const float*)d_in[3];
    const float* bias = (const float*)d_in[4];
    const float* outW = (const float*)d_in[5];
    const float* outb = (const float*)d_in[6];
    const float* lng  = (const float*)d_in[7];
    const float* lnb  = (const float*)d_in[8];

    const int N  = in_sizes[0] / D;
    const int E  = in_sizes[1] / 2;
    const int NT = out_size / D;

    const int* srcp = edge;
    const int* dstp = edge + E;

    auto align256 = [](size_t v) { return (v + 255) & ~(size_t)255; };
    auto cdiv = [](int a, int b) { return (a + b - 1) / b; };

    const int CHUNK = cdiv(E, 256);          // pass-A chunk
    const int NBLK  = cdiv(E, CHUNK);        // <= 256
    const int NBKT  = cdiv(N, 256);          // dst buckets
    const int NB    = cdiv(N, 1024);         // rowptr scan blocks

    size_t ybytes = (size_t)NT * D * 4;
    size_t hb     = (size_t)N * D * 2;
    size_t hbytes = align256(hb > ybytes ? hb : ybytes);

    char* wp = (char*)d_ws;
    size_t off = 0;
    void* hbuf   = (void*)(wp + off); off += hbytes;
    unsigned short* wbf = (unsigned short*)(wp + off); off += align256((size_t)3 * D * D * 2);
    int*  rowptr = (int*)(wp + off);  off += align256((size_t)(N + 1) * 4);
    int*  cnt    = (int*)(wp + off);  off += align256((size_t)N * 4);
    int*  slist  = (int*)(wp + off);  off += align256((size_t)E * 4);
    int2* bout   = (int2*)(wp + off); off += align256((size_t)E * 8);
    int*  bh     = (int*)(wp + off);  off += align256((size_t)NBIN * NBLK * 4);
    int*  tot    = (int*)(wp + off);  off += align256((size_t)NBIN * 4);
    int*  bases  = (int*)(wp + off);  off += align256((size_t)(NBIN + 1) * 4);
    int*  bsum   = (int*)(wp + off);
    unsigned int* xb = (unsigned int*)d_out;   // bf16 activations in d_out
    float* ybuf = (float*)hbuf;                // head GEMM out reuses h buffer
    (void)n_in; (void)ws_size;

    // ---- weight transpose+cast ----
    transpose_w2<<<24, 256, 0, stream>>>(W, outW, wbf);

    // ---- CSR build (LDS-bucketed) ----
    hist_pass<<<NBLK, 256, 0, stream>>>(dstp, bh, E, CHUNK, NBLK);
    bin_scan<<<NBIN, 256, 0, stream>>>(bh, tot, NBLK);
    base_scan<<<1, 256, 0, stream>>>(tot, bases);
    scatter_bucket<<<NBLK, 256, 0, stream>>>(dstp, srcp, bh, bases, bout, E, CHUNK, NBLK);
    count_bucket<<<NBKT, 256, 0, stream>>>(bout, bases, cnt, N);
    scan_blocks<<<NB, 256, 0, stream>>>(cnt, rowptr, bsum, N);
    scan_bsums<<<1, 64, 0, stream>>>(bsum, NB);
    scan_add<<<NB, 256, 0, stream>>>(rowptr, bsum, N);
    fill_bucket<<<NBKT, 256, 0, stream>>>(bout, bases, rowptr, slist, N);

    // ---- layer 0: h = x @ W0 (f32 in, bf16 out) ----
    gemm_mfma<0,1,0><<<cdiv(N, 64), 256, 0, stream>>>(x, wbf, nullptr, hbuf, N);
    aggregate<<<cdiv(N, 4), 256, 0, stream>>>((unsigned int*)hbuf, rowptr, slist,
                                              att, bias, xb, N);
    // ---- layer 1: h = gelu(x) @ W1 (bf16 in, bf16 out) ----
    gemm_mfma<1,1,1><<<cdiv(N, 64), 256, 0, stream>>>(xb, wbf + D * D, nullptr, hbuf, N);
    aggregate<<<cdiv(N, 4), 256, 0, stream>>>((unsigned int*)hbuf, rowptr, slist,
                                              att + H * C, bias + D, xb, N);
    // ---- head: y = x @ outW + outb (bf16 in, f32 out), then LN ----
    gemm_mfma<1,0,0><<<cdiv(NT, 64), 256, 0, stream>>>(xb, wbf + 2 * D * D, outb, ybuf, NT);
    ln_kernel<<<cdiv(NT, 4), 256, 0, stream>>>(ybuf, lng, lnb, (float*)d_out, NT);
}